// Round 13
// baseline (485.875 us; speedup 1.0000x reference)
//
#include <hip/hip_runtime.h>
#include <math.h>

#define HID 128
#define GRP 256
#define INF 9
#define OUTF 10
#define NPART 8

typedef _Float16 half8 __attribute__((ext_vector_type(8)));
typedef _Float16 h2 __attribute__((ext_vector_type(2)));
typedef __attribute__((ext_vector_type(4))) float f32x4;

__device__ __forceinline__ int2 nt_load_int2(const int2* p) {
    long long v = __builtin_nontemporal_load((const long long*)p);
    int2 r; r.x = (int)(v & 0xffffffffLL); r.y = (int)(v >> 32);
    return r;
}

// ---------------- histogram over dst (8-way XCD-partitioned) + W-prep ----------------
__global__ void hist_prepw_kernel(const int* __restrict__ ei, int* __restrict__ cnt_part,
                                  int E, int n,
                                  const float* __restrict__ W1, const float* __restrict__ W2,
                                  const float* __restrict__ W3,
                                  _Float16* __restrict__ Whi, _Float16* __restrict__ Wlo) {
    int e = blockIdx.x * 256 + threadIdx.x;
    if (e < E) atomicAdd(&cnt_part[(size_t)(blockIdx.x & 7) * n + ei[E + e]], 1);
    if (blockIdx.x < 192) {
        int l = blockIdx.x >> 6;                       // 0..2 -> layers 1..3
        int idx = (blockIdx.x & 63) * 256 + threadIdx.x;   // 0..16383
        const float* W = (l == 0) ? W1 : (l == 1) ? W2 : W3;
        int nn = idx >> 7, k = idx & 127;
        float w = W[k * HID + nn];
        _Float16 hi = (_Float16)w;
        _Float16 lo = (_Float16)(w - (float)hi);
        int nt = nn >> 4, l16 = nn & 15;
        int kc = k >> 5, quad = (k >> 3) & 3, j = k & 7;
        size_t off = (size_t)(l + 1) * HID * HID +
                     ((((nt * 4 + kc) * 4 + quad) * 16 + l16) * 8 + j);
        Whi[off] = hi;
        Wlo[off] = lo;
    }
}

// ---------------- parallel scan phase A: per-1024-chunk sums (sums 8 partials) --------
__global__ __launch_bounds__(256) void scanA_kernel(const int* __restrict__ cnt_part,
                                                    int* __restrict__ bsum, int n) {
    int tid = threadIdx.x;
    int base = blockIdx.x * 1024 + tid * 4;
    int s = 0;
    #pragma unroll
    for (int i = 0; i < 4; i++) {
        int idx = base + i;
        if (idx < n) {
            #pragma unroll
            for (int x = 0; x < NPART; x++) s += cnt_part[(size_t)x * n + idx];
        }
    }
    #pragma unroll
    for (int off = 32; off > 0; off >>= 1) s += __shfl_down(s, off);
    __shared__ int ws[4];
    if ((tid & 63) == 0) ws[tid >> 6] = s;
    __syncthreads();
    if (tid == 0) bsum[blockIdx.x] = ws[0] + ws[1] + ws[2] + ws[3];
}

// ---------------- phase C: local scan + per-block prefix of RAW bsum (scanB deleted) --
// v12: each block reduces bsum[0..blockIdx) itself (NB<=49 < 256); the block owning
// idx n-1 writes row_ptr[n]. Removes the serial single-block scanB dispatch.
__global__ __launch_bounds__(256) void scanC_kernel(const int* __restrict__ cnt_part,
                                                    const int* __restrict__ bsum,
                                                    const int* __restrict__ batch,
                                                    int* __restrict__ row_ptr,
                                                    int* __restrict__ cursor_part,
                                                    float* __restrict__ dinv,
                                                    int* __restrict__ gstart,
                                                    int* __restrict__ gend, int n) {
    int tid = threadIdx.x;
    int lane = tid & 63, wid = tid >> 6;
    int idx0 = blockIdx.x * 1024 + tid * 4;
    int v[4];
    #pragma unroll
    for (int i = 0; i < 4; i++) {
        int idx = idx0 + i;
        int s = 0;
        if (idx < n) {
            #pragma unroll
            for (int x = 0; x < NPART; x++) s += cnt_part[(size_t)x * n + idx];
        }
        v[i] = s;
    }
    int s = v[0] + v[1] + v[2] + v[3];
    int ps = s;
    #pragma unroll
    for (int off = 1; off < 64; off <<= 1) {
        int t = __shfl_up(ps, off);
        if (lane >= off) ps += t;
    }
    // per-block prefix over raw bsum (sum of chunks before this one)
    int pv = (tid < blockIdx.x) ? bsum[tid] : 0;
    #pragma unroll
    for (int off = 32; off > 0; off >>= 1) pv += __shfl_down(pv, off);
    __shared__ int wsum[4];
    __shared__ int wpre[4];
    if (lane == 63) wsum[wid] = ps;
    if (lane == 0) wpre[wid] = pv;
    __syncthreads();
    int pre = wpre[0] + wpre[1] + wpre[2] + wpre[3];
    int woff = 0;
    #pragma unroll
    for (int i = 0; i < 4; i++) if (i < wid) woff += wsum[i];
    int run = pre + woff + (ps - s);
    #pragma unroll
    for (int i = 0; i < 4; i++) {
        int idx = idx0 + i;
        if (idx < n) {
            row_ptr[idx] = run;
            dinv[idx] = rsqrtf((float)(v[i] + 1));
            int b = run;
            #pragma unroll
            for (int x = 0; x < NPART; x++) {
                cursor_part[(size_t)x * n + idx] = b;
                b += cnt_part[(size_t)x * n + idx];
            }
            run += v[i];
            int bt = batch[idx];
            if (idx == 0 || batch[idx - 1] != bt) gstart[bt] = idx;
            if (idx == n - 1 || batch[idx + 1] != bt) {
                gend[bt] = idx + 1;
            }
            if (idx == n - 1) row_ptr[n] = run;   // total = E
        }
    }
}

// ---------------- CSR fill: partitioned cursors; PLAIN cached store ----------------
__global__ void fill_kernel(const int* __restrict__ ei, int* __restrict__ cursor_part,
                            const float* __restrict__ dinv,
                            int2* __restrict__ csr, int E, int n) {
    int e = blockIdx.x * blockDim.x + threadIdx.x;
    if (e >= E) return;
    int s = ei[e], d = ei[E + e];
    int pos = atomicAdd(&cursor_part[(size_t)(blockIdx.x & 7) * n + d], 1);
    long long v = ((long long)__float_as_int(dinv[s] * dinv[d]) << 32) | (unsigned)s;
    *(long long*)&csr[pos] = v;
}

// ---------------- per-column reduce of per-block stat partials ----------------
__global__ __launch_bounds__(256) void statreduce_kernel(const float* __restrict__ part,
                                                         int nb, float* __restrict__ statOut) {
    int j = blockIdx.x;
    int tid = threadIdx.x;
    float s = 0.0f;
    for (int b = tid; b < nb; b += 256) s += part[(size_t)b * 256 + j];
    #pragma unroll
    for (int off = 32; off > 0; off >>= 1) s += __shfl_down(s, off);
    __shared__ float ws[4];
    if ((tid & 63) == 0) ws[tid >> 6] = s;
    __syncthreads();
    if (tid == 0) statOut[j] = ws[0] + ws[1] + ws[2] + ws[3];
}

// ---------------- rational activation ----------------
__device__ __forceinline__ float rational_act(float xv, const float* __restrict__ a,
                                              const float* __restrict__ q) {
    float P = a[5];
    P = fmaf(P, xv, a[4]); P = fmaf(P, xv, a[3]); P = fmaf(P, xv, a[2]);
    P = fmaf(P, xv, a[1]); P = fmaf(P, xv, a[0]);
    float Q = q[3];
    Q = fmaf(Q, xv, q[2]); Q = fmaf(Q, xv, q[1]); Q = fmaf(Q, xv, q[0]);
    Q *= xv;
    return P / (1.0f + fabsf(Q));
}

// ---------------- layer-0 FUSED: gather x + (9x128 matvec) + rational + stats --------
// v12: absorbs aggx_kernel. 16 nodes/block, 16-lane groups gather x rows over CSR
// (lane<9 holds channel); agg broadcast in-group via shfl; each lane computes 8 cols.
// Removes the aggX buffer round-trip and one dispatch.
__global__ __launch_bounds__(256) void gemm0_fused_kernel(const float* __restrict__ x,
                                                          const int* __restrict__ row_ptr,
                                                          const int2* __restrict__ csr,
                                                          const float* __restrict__ dinv,
                                                          const float* __restrict__ W0,
                                                          const float* __restrict__ b0,
                                                          const float* __restrict__ rat_num,
                                                          const float* __restrict__ rat_den,
                                                          const int* __restrict__ cl_assign,
                                                          _Float16* __restrict__ act,
                                                          float* __restrict__ cagg,
                                                          float* __restrict__ part, int n) {
    __shared__ float Ws[INF * HID];
    __shared__ float s_num[120], s_den[80];
    __shared__ int s_cl[HID];
    __shared__ float s_b[HID];
    __shared__ float s_sum[HID], s_sq[HID];
    int tid = threadIdx.x;
    for (int i = tid; i < INF * HID; i += 256) Ws[i] = W0[i];
    if (tid < 120) s_num[tid] = rat_num[tid];
    if (tid < 80) s_den[tid] = rat_den[tid];
    if (tid < HID) {
        s_cl[tid] = cl_assign[tid];
        s_b[tid] = b0[tid];
        s_sum[tid] = 0.0f; s_sq[tid] = 0.0f;
    }
    __syncthreads();
    int grp = tid >> 4, glane = tid & 15;
    int grpbase = tid & 48;           // group base lane within the wave
    int node = blockIdx.x * 16 + grp;
    float accv = 0.0f, cfs = 0.0f;
    if (node < n) {
        float di = dinv[node];
        float self = di * di;
        accv = (glane < INF) ? x[node * INF + glane] * self : 0.0f;
        cfs = self;
        int beg = row_ptr[node], end = row_ptr[node + 1];
        for (int j = beg; j < end; j++) {
            int2 p = nt_load_int2(&csr[j]);
            float cf = __int_as_float(p.y);
            cfs += cf;
            if (glane < INF) accv = fmaf(cf, x[p.x * INF + glane], accv);
        }
        if (glane == 0) cagg[node] = cfs;
    }
    // broadcast agg channels within the 16-lane group
    float av[INF];
    #pragma unroll
    for (int k = 0; k < INF; k++) av[k] = __shfl(accv, grpbase + k, 64);
    if (node < n) {
        half8 o;
        #pragma unroll
        for (int t = 0; t < 8; t++) {
            int c = glane * 8 + t;
            float acc = s_b[c];
            #pragma unroll
            for (int k = 0; k < INF; k++) acc = fmaf(av[k], Ws[k * HID + c], acc);
            float r = rational_act(acc, s_num + s_cl[c] * 6, s_den + s_cl[c] * 4);
            o[t] = (_Float16)r;
            atomicAdd(&s_sum[c], r);
            atomicAdd(&s_sq[c], r * r);
        }
        __builtin_nontemporal_store(o, (half8*)&act[(size_t)node * HID + glane * 8]);
    }
    __syncthreads();
    float pv = (tid < 128) ? s_sum[tid] : s_sq[tid - 128];
    __builtin_nontemporal_store(pv, &part[(size_t)blockIdx.x * 256 + tid]);
}

// ---------------- fused layer (1-3): gather-agg -> LDS A-tile -> fp16 MFMA -> rational ----------------
// v11 config kept: 16-row tile + __launch_bounds__(256, 5). Launch-bounds sweep CLOSED:
// (256,5) -> VGPR 48, no spill, 48.5us; (256,6) -> mild spill; (256,8) -> heavy spill.
__global__ __launch_bounds__(256, 5) void layer_fused_kernel(const _Float16* __restrict__ act,
                                                          const int2* __restrict__ csr,
                                                          const int* __restrict__ row_ptr,
                                                          const float* __restrict__ dinv,
                                                          const float* __restrict__ cagg,
                                                          const float* __restrict__ statPrev,
                                                          const float* __restrict__ gPrev,
                                                          const float* __restrict__ bePrev,
                                                          const _Float16* __restrict__ Whi,
                                                          const _Float16* __restrict__ Wlo,
                                                          const float* __restrict__ bias,
                                                          const float* __restrict__ rat_num,
                                                          const float* __restrict__ rat_den,
                                                          const int* __restrict__ cl_assign,
                                                          _Float16* __restrict__ actOut,
                                                          float* __restrict__ part, int n) {
    __shared__ _Float16 Alds[16 * 136];
    __shared__ float s_bnw[HID], s_bnu[HID];
    __shared__ float s_num[120], s_den[80];
    __shared__ int s_cl[HID];
    __shared__ float s_bias[HID];
    __shared__ float s_sum[HID], s_sq[HID];
    int tid = threadIdx.x;
    if (tid < 120) s_num[tid] = rat_num[tid];
    if (tid < 80) s_den[tid] = rat_den[tid];
    if (tid < HID) {
        float inv_n = 1.0f / (float)n;
        float mean = statPrev[tid] * inv_n;
        float var = statPrev[HID + tid] * inv_n - mean * mean;
        float w = gPrev[tid] * rsqrtf(var + 1e-5f);
        s_bnw[tid] = w;
        s_bnu[tid] = bePrev[tid] - mean * w;
        s_cl[tid] = cl_assign[tid];
        s_bias[tid] = bias[tid];
        s_sum[tid] = 0.0f; s_sq[tid] = 0.0f;
    }
    __syncthreads();

    int r0 = blockIdx.x * 16;
    int grp = tid >> 4, glane = tid & 15;
    int grpbase = tid & 48;               // group base lane within the wave
    const half8* act8 = (const half8*)act;

    // ---- one node per 16-lane group ----
    int node = r0 + grp;
    int beg = 0, end = 0;
    if (node < n) { beg = row_ptr[node]; end = row_ptr[node + 1]; }
    int2 pfirst = make_int2(0, 0); float cfirst = 0.0f;
    {
        int rem = end - beg;
        if (rem > 0) {
            int m = rem < 16 ? rem : 16;
            int2 p = nt_load_int2(&csr[beg + (glane < m ? glane : m - 1)]);   // clamped
            pfirst = p;
            cfirst = (glane < m) ? __int_as_float(p.y) : 0.0f;  // coef 0 for pad slots
        }
    }

    // process 8 edge-slots [off..off+8) of the current chunk held in (cp, cc)
    #define PROCESS8(off)                                                              \
        {                                                                              \
            int srcs[8]; float cfs[8];                                                 \
            _Pragma("unroll")                                                          \
            for (int u = 0; u < 8; u++) {                                              \
                srcs[u] = __shfl(cp.x, grpbase + (off) + u, 64);                       \
                cfs[u]  = __shfl(cc,   grpbase + (off) + u, 64);                       \
            }                                                                          \
            half8 v[8];                                                                \
            _Pragma("unroll")                                                          \
            for (int u = 0; u < 8; u++) v[u] = act8[srcs[u] * 16 + glane];             \
            _Pragma("unroll")                                                          \
            for (int u = 0; u < 8; u++) {                                              \
                _Pragma("unroll")                                                      \
                for (int t = 0; t < 8; t++)                                            \
                    acc[t] = fmaf(cfs[u], (float)v[u][t], acc[t]);                     \
            }                                                                          \
        }

    {
        half8 o;
        if (node < n) {
            float di = dinv[node];
            float selfc = di * di;
            half8 sv = act8[node * 16 + glane];
            float acc[8];
            #pragma unroll
            for (int t = 0; t < 8; t++) acc[t] = (float)sv[t] * selfc;
            int base = beg;
            if (base < end) {
                int2 cp = pfirst; float cc = cfirst;
                for (;;) {
                    int m = end - base; if (m > 16) m = 16;
                    PROCESS8(0)
                    if (m > 8) PROCESS8(8)
                    base += 16;
                    if (base >= end) break;
                    int mn = end - base; if (mn > 16) mn = 16;
                    int2 p = nt_load_int2(&csr[base + (glane < mn ? glane : mn - 1)]);
                    cp = p;
                    cc = (glane < mn) ? __int_as_float(p.y) : 0.0f;
                }
            }
            float cg = cagg[node];
            #pragma unroll
            for (int t = 0; t < 8; t++) {
                int c = glane * 8 + t;
                o[t] = (_Float16)fmaf(s_bnw[c], acc[t], s_bnu[c] * cg);
            }
        } else {
            #pragma unroll
            for (int t = 0; t < 8; t++) o[t] = (_Float16)0.0f;
        }
        *(half8*)&Alds[grp * 136 + glane * 8] = o;
    }
    #undef PROCESS8
    __syncthreads();

    // ---- MFMA phase: wave w -> 16 rows x col quarter [w*32, w*32+32) ----
    int w = tid >> 6, l64 = tid & 63;
    int quad = l64 >> 4, l16 = l64 & 15;
    const half8* Bh8 = (const half8*)Whi;
    const half8* Bl8 = (const half8*)Wlo;
    f32x4 acc[2];
    #pragma unroll
    for (int j = 0; j < 2; j++) acc[j] = (f32x4){0.f, 0.f, 0.f, 0.f};
    #pragma unroll
    for (int kc = 0; kc < 4; kc++) {
        half8 a = *(const half8*)&Alds[l16 * 136 + kc * 32 + quad * 8];
        #pragma unroll
        for (int j = 0; j < 2; j++) {
            int ntg = w * 2 + j;
            half8 bh = Bh8[(ntg * 4 + kc) * 64 + l64];
            half8 bl = Bl8[(ntg * 4 + kc) * 64 + l64];
            acc[j] = __builtin_amdgcn_mfma_f32_16x16x32_f16(a, bh, acc[j], 0, 0, 0);
            acc[j] = __builtin_amdgcn_mfma_f32_16x16x32_f16(a, bl, acc[j], 0, 0, 0);
        }
    }
    __syncthreads();   // all waves done reading A-tile; Alds reused as output stage

    // ---- epilogue: bias + rational -> LDS stage + stats (C layout: col=l16, row=quad*4+reg) ----
    float ps[2], pq[2];
    #pragma unroll
    for (int j = 0; j < 2; j++) { ps[j] = 0.0f; pq[j] = 0.0f; }
    #pragma unroll
    for (int reg = 0; reg < 4; reg++) {
        int lrow = quad * 4 + reg;
        int row = r0 + lrow;
        bool live = (row < n);
        #pragma unroll
        for (int j = 0; j < 2; j++) {
            int col = (w * 2 + j) * 16 + l16;
            float v = acc[j][reg] + s_bias[col];
            float r = rational_act(v, s_num + s_cl[col] * 6, s_den + s_cl[col] * 4);
            Alds[lrow * 136 + col] = (_Float16)r;
            if (live) { ps[j] += r; pq[j] = fmaf(r, r, pq[j]); }
        }
    }
    // cross-quad reduce first -> 4x fewer LDS atomics, no same-address serialization
    #pragma unroll
    for (int j = 0; j < 2; j++) {
        float a2 = ps[j] + __shfl_xor(ps[j], 16, 64);
        a2 += __shfl_xor(a2, 32, 64);
        float b2 = pq[j] + __shfl_xor(pq[j], 16, 64);
        b2 += __shfl_xor(b2, 32, 64);
        if (quad == 0) {
            int col = (w * 2 + j) * 16 + l16;
            atomicAdd(&s_sum[col], a2);
            atomicAdd(&s_sq[col], b2);
        }
    }
    __syncthreads();
    // per-block stat partials: contention-free 1KB full-line NT store
    {
        float pv = (tid < 128) ? s_sum[tid] : s_sq[tid - 128];
        __builtin_nontemporal_store(pv, &part[(size_t)blockIdx.x * 256 + tid]);
    }
    // ---- full-line NT stores: 1 x half8 per thread, 256B rows, 256B-aligned base ----
    {
        int lrow = tid >> 4, lc = (tid & 15) * 8;
        int row = r0 + lrow;
        if (row < n) {
            half8 v = *(const half8*)&Alds[lrow * 136 + lc];
            __builtin_nontemporal_store(v, (half8*)&actOut[(size_t)row * HID + lc]);
        }
    }
}

// ---------------- fused pool (+final BN affine from stats) + 3-stage MLP ----------------
__global__ __launch_bounds__(256) void poolmlp_kernel(const _Float16* __restrict__ act,
                                                      const int* __restrict__ gstart,
                                                      const int* __restrict__ gend,
                                                      const float* __restrict__ stat,
                                                      const float* __restrict__ g3,
                                                      const float* __restrict__ be3,
                                                      const float* __restrict__ HW1,
                                                      const float* __restrict__ Hb1,
                                                      const float* __restrict__ HW2,
                                                      const float* __restrict__ Hb2,
                                                      const float* __restrict__ HW3,
                                                      const float* __restrict__ Hb3,
                                                      float* __restrict__ out, int n) {
    __shared__ float red[16][HID];
    __shared__ float s_pool[HID];
    __shared__ float s_z[HID];
    int gi = blockIdx.x;
    int tid = threadIdx.x;
    int rg = tid >> 4, lane = tid & 15;
    int s = gstart[gi], e = gend[gi];
    const half8* act8 = (const half8*)act;
    float a[8];
    #pragma unroll
    for (int t = 0; t < 8; t++) a[t] = 0.0f;
    for (int r = s + rg; r < e; r += 16) {
        half8 v = act8[r * 16 + lane];
        #pragma unroll
        for (int t = 0; t < 8; t++) a[t] += (float)v[t];
    }
    #pragma unroll
    for (int t = 0; t < 8; t++) red[rg][lane * 8 + t] = a[t];
    __syncthreads();
    if (tid < HID) {
        float tot = 0.0f;
        #pragma unroll
        for (int i = 0; i < 16; i++) tot += red[i][tid];
        int cnt = e - s;
        float pooled = 0.0f;
        if (cnt > 0) {
            float inv_n = 1.0f / (float)n;
            float mean = stat[tid] * inv_n;
            float var = stat[HID + tid] * inv_n - mean * mean;
            float w = g3[tid] * rsqrtf(var + 1e-5f);
            float u = be3[tid] - mean * w;
            pooled = fmaf(w, tot / (float)cnt, u);
        }
        s_pool[tid] = pooled;
    }
    __syncthreads();
    if (tid < HID) {
        float acc = Hb1[tid];
        #pragma unroll 8
        for (int k = 0; k < HID; k++) acc = fmaf(s_pool[k], HW1[k * HID + tid], acc);
        s_z[tid] = 0.5f * acc * (1.0f + erff(acc * 0.70710678118654752f));
    }
    __syncthreads();
    if (tid < HID) {
        float acc = Hb2[tid];
        #pragma unroll 8
        for (int k = 0; k < HID; k++) acc = fmaf(s_z[k], HW2[k * HID + tid], acc);
        s_pool[tid] = 0.5f * acc * (1.0f + erff(acc * 0.70710678118654752f));
    }
    __syncthreads();
    if (tid < OUTF) {
        float acc = Hb3[tid];
        #pragma unroll 8
        for (int k = 0; k < HID; k++) acc = fmaf(s_pool[k], HW3[k * OUTF + tid], acc);
        out[gi * OUTF + tid] = acc;
    }
}

extern "C" void kernel_launch(void* const* d_in, const int* in_sizes, int n_in,
                              void* d_out, int out_size, void* d_ws, size_t ws_size,
                              hipStream_t stream) {
    const float* x          = (const float*)d_in[0];
    const int*   edge_index = (const int*)d_in[1];
    const int*   batch      = (const int*)d_in[2];
    const float* W[4]  = {(const float*)d_in[3], (const float*)d_in[7], (const float*)d_in[11], (const float*)d_in[15]};
    const float* bL[4] = {(const float*)d_in[4], (const float*)d_in[8], (const float*)d_in[12], (const float*)d_in[16]};
    const float* gL[4] = {(const float*)d_in[5], (const float*)d_in[9], (const float*)d_in[13], (const float*)d_in[17]};
    const float* beL[4]= {(const float*)d_in[6], (const float*)d_in[10], (const float*)d_in[14], (const float*)d_in[18]};
    const float* rat_num = (const float*)d_in[19];
    const float* rat_den = (const float*)d_in[20];
    const int*   cl_assign = (const int*)d_in[21];
    const float* HW1 = (const float*)d_in[22];
    const float* Hb1 = (const float*)d_in[23];
    const float* HW2 = (const float*)d_in[24];
    const float* Hb2 = (const float*)d_in[25];
    const float* HW3 = (const float*)d_in[26];
    const float* Hb3 = (const float*)d_in[27];
    float* out = (float*)d_out;

    const int N = in_sizes[0] / INF;
    const int E = in_sizes[1] / 2;
    const int NB = (N + 1023) / 1024;
    const int layer_grid = (N + 15) / 16;

    // ---- workspace layout (dword offsets, every buffer 256B-aligned) ----
    char* wsb = (char*)d_ws;
    size_t o = 0;
    #define ALIGNB o = (o + 63) & ~(size_t)63;
    int*   cnt_part = (int*)(wsb + o * 4);  o += (size_t)NPART * N; ALIGNB  // zeroed
    int*   gstart  = (int*)(wsb + o * 4);  o += GRP; ALIGNB         // zeroed
    int*   gend    = (int*)(wsb + o * 4);  o += GRP; ALIGNB         // zeroed
    float* bnstat  = (float*)(wsb + o * 4); o += 4 * 256; ALIGNB    // zeroed
    size_t zero_elems = o;
    int*   bsum    = (int*)(wsb + o * 4);  o += ((NB + 63) & ~63); ALIGNB
    int*   cursor_part = (int*)(wsb + o * 4);  o += (size_t)NPART * N; ALIGNB
    int*   row_ptr = (int*)(wsb + o * 4);  o += N + 1; ALIGNB
    float* dinv    = (float*)(wsb + o * 4); o += N; ALIGNB
    float* cagg    = (float*)(wsb + o * 4); o += N; ALIGNB
    int2*  csr     = (int2*)(wsb + o * 4);  o += 2 * (size_t)E; ALIGNB
    _Float16* WhiAll = (_Float16*)(wsb + o * 4); o += 4 * HID * HID / 2; ALIGNB
    _Float16* WloAll = (_Float16*)(wsb + o * 4); o += 4 * HID * HID / 2; ALIGNB
    _Float16* actA  = (_Float16*)(wsb + o * 4); o += (size_t)N * HID / 2; ALIGNB
    _Float16* actB  = (_Float16*)(wsb + o * 4); o += (size_t)N * HID / 2; ALIGNB
    float* part    = (float*)(wsb + o * 4); o += (size_t)layer_grid * 256;

    hipMemsetAsync(d_ws, 0, zero_elems * 4, stream);

    int eb = (E + 255) / 256;
    hist_prepw_kernel<<<eb, 256, 0, stream>>>(edge_index, cnt_part, E, N, W[1], W[2], W[3],
                                              WhiAll, WloAll);
    scanA_kernel<<<NB, 256, 0, stream>>>(cnt_part, bsum, N);
    scanC_kernel<<<NB, 256, 0, stream>>>(cnt_part, bsum, batch, row_ptr, cursor_part, dinv,
                                         gstart, gend, N);
    fill_kernel<<<eb, 256, 0, stream>>>(edge_index, cursor_part, dinv, csr, E, N);

    // layer 0 (gather + matvec fused)
    gemm0_fused_kernel<<<layer_grid, 256, 0, stream>>>(x, row_ptr, csr, dinv, W[0], bL[0],
                                                       rat_num, rat_den, cl_assign,
                                                       actA, cagg, part, N);
    statreduce_kernel<<<256, 256, 0, stream>>>(part, layer_grid, bnstat);

    _Float16* ain = actA;
    _Float16* aout = actB;
    for (int l = 1; l < 4; l++) {
        layer_fused_kernel<<<layer_grid, 256, 0, stream>>>(ain, csr, row_ptr, dinv, cagg,
                                                           bnstat + (l - 1) * 256,
                                                           gL[l - 1], beL[l - 1],
                                                           WhiAll + (size_t)l * HID * HID,
                                                           WloAll + (size_t)l * HID * HID,
                                                           bL[l], rat_num, rat_den, cl_assign,
                                                           aout, bnstat ? part : part, N);
        statreduce_kernel<<<256, 256, 0, stream>>>(part, layer_grid, bnstat + l * 256);
        _Float16* t = ain; ain = aout; aout = t;
    }
    poolmlp_kernel<<<GRP, 256, 0, stream>>>(ain, gstart, gend, bnstat + 3 * 256,
                                            gL[3], beL[3], HW1, Hb1, HW2, Hb2, HW3, Hb3,
                                            out, N);
}

// Round 14
// 436.684 us; speedup vs baseline: 1.1126x; 1.1126x over previous
//
#include <hip/hip_runtime.h>
#include <math.h>

#define HID 128
#define GRP 256
#define INF 9
#define OUTF 10
#define NPART 8

typedef _Float16 half8 __attribute__((ext_vector_type(8)));
typedef _Float16 h2 __attribute__((ext_vector_type(2)));
typedef __attribute__((ext_vector_type(4))) float f32x4;

__device__ __forceinline__ int2 nt_load_int2(const int2* p) {
    long long v = __builtin_nontemporal_load((const long long*)p);
    int2 r; r.x = (int)(v & 0xffffffffLL); r.y = (int)(v >> 32);
    return r;
}

// ---------------- histogram over dst (8-way XCD-partitioned) + W-prep ----------------
__global__ void hist_prepw_kernel(const int* __restrict__ ei, int* __restrict__ cnt_part,
                                  int E, int n,
                                  const float* __restrict__ W1, const float* __restrict__ W2,
                                  const float* __restrict__ W3,
                                  _Float16* __restrict__ Whi, _Float16* __restrict__ Wlo) {
    int e = blockIdx.x * 256 + threadIdx.x;
    if (e < E) atomicAdd(&cnt_part[(size_t)(blockIdx.x & 7) * n + ei[E + e]], 1);
    if (blockIdx.x < 192) {
        int l = blockIdx.x >> 6;                       // 0..2 -> layers 1..3
        int idx = (blockIdx.x & 63) * 256 + threadIdx.x;   // 0..16383
        const float* W = (l == 0) ? W1 : (l == 1) ? W2 : W3;
        int nn = idx >> 7, k = idx & 127;
        float w = W[k * HID + nn];
        _Float16 hi = (_Float16)w;
        _Float16 lo = (_Float16)(w - (float)hi);
        int nt = nn >> 4, l16 = nn & 15;
        int kc = k >> 5, quad = (k >> 3) & 3, j = k & 7;
        size_t off = (size_t)(l + 1) * HID * HID +
                     ((((nt * 4 + kc) * 4 + quad) * 16 + l16) * 8 + j);
        Whi[off] = hi;
        Wlo[off] = lo;
    }
}

// ---------------- parallel scan phase A: per-1024-chunk sums (sums 8 partials) --------
__global__ __launch_bounds__(256) void scanA_kernel(const int* __restrict__ cnt_part,
                                                    int* __restrict__ bsum, int n) {
    int tid = threadIdx.x;
    int base = blockIdx.x * 1024 + tid * 4;
    int s = 0;
    #pragma unroll
    for (int i = 0; i < 4; i++) {
        int idx = base + i;
        if (idx < n) {
            #pragma unroll
            for (int x = 0; x < NPART; x++) s += cnt_part[(size_t)x * n + idx];
        }
    }
    #pragma unroll
    for (int off = 32; off > 0; off >>= 1) s += __shfl_down(s, off);
    __shared__ int ws[4];
    if ((tid & 63) == 0) ws[tid >> 6] = s;
    __syncthreads();
    if (tid == 0) bsum[blockIdx.x] = ws[0] + ws[1] + ws[2] + ws[3];
}

// ---------------- phase C: local scan + per-block prefix of RAW bsum (no scanB) -------
__global__ __launch_bounds__(256) void scanC_kernel(const int* __restrict__ cnt_part,
                                                    const int* __restrict__ bsum,
                                                    const int* __restrict__ batch,
                                                    int* __restrict__ row_ptr,
                                                    int* __restrict__ cursor_part,
                                                    float* __restrict__ dinv,
                                                    int* __restrict__ gstart,
                                                    int* __restrict__ gend, int n) {
    int tid = threadIdx.x;
    int lane = tid & 63, wid = tid >> 6;
    int idx0 = blockIdx.x * 1024 + tid * 4;
    int v[4];
    #pragma unroll
    for (int i = 0; i < 4; i++) {
        int idx = idx0 + i;
        int s = 0;
        if (idx < n) {
            #pragma unroll
            for (int x = 0; x < NPART; x++) s += cnt_part[(size_t)x * n + idx];
        }
        v[i] = s;
    }
    int s = v[0] + v[1] + v[2] + v[3];
    int ps = s;
    #pragma unroll
    for (int off = 1; off < 64; off <<= 1) {
        int t = __shfl_up(ps, off);
        if (lane >= off) ps += t;
    }
    // per-block prefix over raw bsum (sum of chunks before this one)
    int pv = (tid < blockIdx.x) ? bsum[tid] : 0;
    #pragma unroll
    for (int off = 32; off > 0; off >>= 1) pv += __shfl_down(pv, off);
    __shared__ int wsum[4];
    __shared__ int wpre[4];
    if (lane == 63) wsum[wid] = ps;
    if (lane == 0) wpre[wid] = pv;
    __syncthreads();
    int pre = wpre[0] + wpre[1] + wpre[2] + wpre[3];
    int woff = 0;
    #pragma unroll
    for (int i = 0; i < 4; i++) if (i < wid) woff += wsum[i];
    int run = pre + woff + (ps - s);
    #pragma unroll
    for (int i = 0; i < 4; i++) {
        int idx = idx0 + i;
        if (idx < n) {
            row_ptr[idx] = run;
            dinv[idx] = rsqrtf((float)(v[i] + 1));
            int b = run;
            #pragma unroll
            for (int x = 0; x < NPART; x++) {
                cursor_part[(size_t)x * n + idx] = b;
                b += cnt_part[(size_t)x * n + idx];
            }
            run += v[i];
            int bt = batch[idx];
            if (idx == 0 || batch[idx - 1] != bt) gstart[bt] = idx;
            if (idx == n - 1 || batch[idx + 1] != bt) {
                gend[bt] = idx + 1;
            }
            if (idx == n - 1) row_ptr[n] = run;   // total = E
        }
    }
}

// ---------------- CSR fill: partitioned cursors; PLAIN cached store ----------------
__global__ void fill_kernel(const int* __restrict__ ei, int* __restrict__ cursor_part,
                            const float* __restrict__ dinv,
                            int2* __restrict__ csr, int E, int n) {
    int e = blockIdx.x * blockDim.x + threadIdx.x;
    if (e >= E) return;
    int s = ei[e], d = ei[E + e];
    int pos = atomicAdd(&cursor_part[(size_t)(blockIdx.x & 7) * n + d], 1);
    long long v = ((long long)__float_as_int(dinv[s] * dinv[d]) << 32) | (unsigned)s;
    *(long long*)&csr[pos] = v;
}

// ---------------- per-column reduce of per-block stat partials ----------------
__global__ __launch_bounds__(256) void statreduce_kernel(const float* __restrict__ part,
                                                         int nb, float* __restrict__ statOut) {
    int j = blockIdx.x;
    int tid = threadIdx.x;
    float s = 0.0f;
    for (int b = tid; b < nb; b += 256) s += part[(size_t)b * 256 + j];
    #pragma unroll
    for (int off = 32; off > 0; off >>= 1) s += __shfl_down(s, off);
    __shared__ float ws[4];
    if ((tid & 63) == 0) ws[tid >> 6] = s;
    __syncthreads();
    if (tid == 0) statOut[j] = ws[0] + ws[1] + ws[2] + ws[3];
}

// ---------------- rational activation ----------------
__device__ __forceinline__ float rational_act(float xv, const float* __restrict__ a,
                                              const float* __restrict__ q) {
    float P = a[5];
    P = fmaf(P, xv, a[4]); P = fmaf(P, xv, a[3]); P = fmaf(P, xv, a[2]);
    P = fmaf(P, xv, a[1]); P = fmaf(P, xv, a[0]);
    float Q = q[3];
    Q = fmaf(Q, xv, q[2]); Q = fmaf(Q, xv, q[1]); Q = fmaf(Q, xv, q[0]);
    Q *= xv;
    return P / (1.0f + fabsf(Q));
}

// ---------------- layer-0 FUSED v2: 8-deep unrolled gather + reg stats ----------------
// v13 fixes v12's two regressions (100us kernel): (1) serial per-edge gather -> PROCESS8-
// style 8-deep unroll (8 independent x-row loads in flight, the layer kernel's proven
// pattern); (2) per-node LDS atomic storm (16 atomics/thread, 4-way same-address, 2.3M
// conflicts) -> register r + shfl_xor(16/32) cross-group reduce, atomics only on 16
// lanes/wave.
__global__ __launch_bounds__(256) void gemm0_fused_kernel(const float* __restrict__ x,
                                                          const int* __restrict__ row_ptr,
                                                          const int2* __restrict__ csr,
                                                          const float* __restrict__ dinv,
                                                          const float* __restrict__ W0,
                                                          const float* __restrict__ b0,
                                                          const float* __restrict__ rat_num,
                                                          const float* __restrict__ rat_den,
                                                          const int* __restrict__ cl_assign,
                                                          _Float16* __restrict__ act,
                                                          float* __restrict__ cagg,
                                                          float* __restrict__ part, int n) {
    __shared__ float Ws[INF * HID];
    __shared__ float s_num[120], s_den[80];
    __shared__ int s_cl[HID];
    __shared__ float s_b[HID];
    __shared__ float s_sum[HID], s_sq[HID];
    int tid = threadIdx.x;
    for (int i = tid; i < INF * HID; i += 256) Ws[i] = W0[i];
    if (tid < 120) s_num[tid] = rat_num[tid];
    if (tid < 80) s_den[tid] = rat_den[tid];
    if (tid < HID) {
        s_cl[tid] = cl_assign[tid];
        s_b[tid] = b0[tid];
        s_sum[tid] = 0.0f; s_sq[tid] = 0.0f;
    }
    __syncthreads();
    int grp = tid >> 4, glane = tid & 15;
    int grpbase = tid & 48;           // group base lane within the wave
    int node = blockIdx.x * 16 + grp;
    int beg = 0, end = 0;
    if (node < n) { beg = row_ptr[node]; end = row_ptr[node + 1]; }
    int2 pfirst = make_int2(0, 0); float cfirst = 0.0f;
    {
        int rem = end - beg;
        if (rem > 0) {
            int m = rem < 16 ? rem : 16;
            int2 p = nt_load_int2(&csr[beg + (glane < m ? glane : m - 1)]);   // clamped
            pfirst = p;
            cfirst = (glane < m) ? __int_as_float(p.y) : 0.0f;
        }
    }

    // 8-deep unrolled gather: broadcast 8 edges, 8 x-loads in flight (lane<9 active)
    #define GPROC8(off)                                                                \
        {                                                                              \
            int srcs[8]; float cfv[8];                                                 \
            _Pragma("unroll")                                                          \
            for (int u = 0; u < 8; u++) {                                              \
                srcs[u] = __shfl(cp.x, grpbase + (off) + u, 64);                       \
                cfv[u]  = __shfl(cc,   grpbase + (off) + u, 64);                       \
            }                                                                          \
            float xv[8];                                                               \
            _Pragma("unroll")                                                          \
            for (int u = 0; u < 8; u++)                                                \
                xv[u] = (glane < INF) ? x[(size_t)srcs[u] * INF + glane] : 0.0f;       \
            _Pragma("unroll")                                                          \
            for (int u = 0; u < 8; u++) {                                              \
                cfs += cfv[u];                                                         \
                accv = fmaf(cfv[u], xv[u], accv);                                      \
            }                                                                          \
        }

    float accv = 0.0f, cfs = 0.0f;
    if (node < n) {
        float di = dinv[node];
        float self = di * di;
        accv = (glane < INF) ? x[(size_t)node * INF + glane] * self : 0.0f;
        cfs = self;
        int base = beg;
        if (base < end) {
            int2 cp = pfirst; float cc = cfirst;
            for (;;) {
                int m = end - base; if (m > 16) m = 16;
                GPROC8(0)
                if (m > 8) GPROC8(8)
                base += 16;
                if (base >= end) break;
                int mn = end - base; if (mn > 16) mn = 16;
                int2 p = nt_load_int2(&csr[base + (glane < mn ? glane : mn - 1)]);
                cp = p;
                cc = (glane < mn) ? __int_as_float(p.y) : 0.0f;
            }
        }
        if (glane == 0) cagg[node] = cfs;
    }
    #undef GPROC8

    // broadcast agg channels within the 16-lane group
    float av[INF];
    #pragma unroll
    for (int k = 0; k < INF; k++) av[k] = __shfl(accv, grpbase + k, 64);

    // matvec + rational; stats in registers
    float r8[8];
    #pragma unroll
    for (int t = 0; t < 8; t++) r8[t] = 0.0f;
    if (node < n) {
        half8 o;
        #pragma unroll
        for (int t = 0; t < 8; t++) {
            int c = glane * 8 + t;
            float acc = s_b[c];
            #pragma unroll
            for (int k = 0; k < INF; k++) acc = fmaf(av[k], Ws[k * HID + c], acc);
            float r = rational_act(acc, s_num + s_cl[c] * 6, s_den + s_cl[c] * 4);
            o[t] = (_Float16)r;
            r8[t] = r;
        }
        __builtin_nontemporal_store(o, (half8*)&act[(size_t)node * HID + glane * 8]);
    }
    // cross-group (within-wave) reduce -> only lanes with grpbase==0 do LDS atomics
    #pragma unroll
    for (int t = 0; t < 8; t++) {
        float a2 = r8[t] + __shfl_xor(r8[t], 16, 64);
        a2 += __shfl_xor(a2, 32, 64);
        float sq = r8[t] * r8[t];
        float b2 = sq + __shfl_xor(sq, 16, 64);
        b2 += __shfl_xor(b2, 32, 64);
        if (grpbase == 0) {
            int c = glane * 8 + t;
            atomicAdd(&s_sum[c], a2);
            atomicAdd(&s_sq[c], b2);
        }
    }
    __syncthreads();
    float pv = (tid < 128) ? s_sum[tid] : s_sq[tid - 128];
    __builtin_nontemporal_store(pv, &part[(size_t)blockIdx.x * 256 + tid]);
}

// ---------------- fused layer (1-3): gather-agg -> LDS A-tile -> fp16 MFMA -> rational ----------------
// v11 config kept: 16-row tile + __launch_bounds__(256, 5). Launch-bounds sweep CLOSED:
// (256,5) -> VGPR 48, no spill, 48.5us; (256,6) -> mild spill; (256,8) -> heavy spill.
__global__ __launch_bounds__(256, 5) void layer_fused_kernel(const _Float16* __restrict__ act,
                                                          const int2* __restrict__ csr,
                                                          const int* __restrict__ row_ptr,
                                                          const float* __restrict__ dinv,
                                                          const float* __restrict__ cagg,
                                                          const float* __restrict__ statPrev,
                                                          const float* __restrict__ gPrev,
                                                          const float* __restrict__ bePrev,
                                                          const _Float16* __restrict__ Whi,
                                                          const _Float16* __restrict__ Wlo,
                                                          const float* __restrict__ bias,
                                                          const float* __restrict__ rat_num,
                                                          const float* __restrict__ rat_den,
                                                          const int* __restrict__ cl_assign,
                                                          _Float16* __restrict__ actOut,
                                                          float* __restrict__ part, int n) {
    __shared__ _Float16 Alds[16 * 136];
    __shared__ float s_bnw[HID], s_bnu[HID];
    __shared__ float s_num[120], s_den[80];
    __shared__ int s_cl[HID];
    __shared__ float s_bias[HID];
    __shared__ float s_sum[HID], s_sq[HID];
    int tid = threadIdx.x;
    if (tid < 120) s_num[tid] = rat_num[tid];
    if (tid < 80) s_den[tid] = rat_den[tid];
    if (tid < HID) {
        float inv_n = 1.0f / (float)n;
        float mean = statPrev[tid] * inv_n;
        float var = statPrev[HID + tid] * inv_n - mean * mean;
        float w = gPrev[tid] * rsqrtf(var + 1e-5f);
        s_bnw[tid] = w;
        s_bnu[tid] = bePrev[tid] - mean * w;
        s_cl[tid] = cl_assign[tid];
        s_bias[tid] = bias[tid];
        s_sum[tid] = 0.0f; s_sq[tid] = 0.0f;
    }
    __syncthreads();

    int r0 = blockIdx.x * 16;
    int grp = tid >> 4, glane = tid & 15;
    int grpbase = tid & 48;               // group base lane within the wave
    const half8* act8 = (const half8*)act;

    // ---- one node per 16-lane group ----
    int node = r0 + grp;
    int beg = 0, end = 0;
    if (node < n) { beg = row_ptr[node]; end = row_ptr[node + 1]; }
    int2 pfirst = make_int2(0, 0); float cfirst = 0.0f;
    {
        int rem = end - beg;
        if (rem > 0) {
            int m = rem < 16 ? rem : 16;
            int2 p = nt_load_int2(&csr[beg + (glane < m ? glane : m - 1)]);   // clamped
            pfirst = p;
            cfirst = (glane < m) ? __int_as_float(p.y) : 0.0f;  // coef 0 for pad slots
        }
    }

    // process 8 edge-slots [off..off+8) of the current chunk held in (cp, cc)
    #define PROCESS8(off)                                                              \
        {                                                                              \
            int srcs[8]; float cfs[8];                                                 \
            _Pragma("unroll")                                                          \
            for (int u = 0; u < 8; u++) {                                              \
                srcs[u] = __shfl(cp.x, grpbase + (off) + u, 64);                       \
                cfs[u]  = __shfl(cc,   grpbase + (off) + u, 64);                       \
            }                                                                          \
            half8 v[8];                                                                \
            _Pragma("unroll")                                                          \
            for (int u = 0; u < 8; u++) v[u] = act8[srcs[u] * 16 + glane];             \
            _Pragma("unroll")                                                          \
            for (int u = 0; u < 8; u++) {                                              \
                _Pragma("unroll")                                                      \
                for (int t = 0; t < 8; t++)                                            \
                    acc[t] = fmaf(cfs[u], (float)v[u][t], acc[t]);                     \
            }                                                                          \
        }

    {
        half8 o;
        if (node < n) {
            float di = dinv[node];
            float selfc = di * di;
            half8 sv = act8[node * 16 + glane];
            float acc[8];
            #pragma unroll
            for (int t = 0; t < 8; t++) acc[t] = (float)sv[t] * selfc;
            int base = beg;
            if (base < end) {
                int2 cp = pfirst; float cc = cfirst;
                for (;;) {
                    int m = end - base; if (m > 16) m = 16;
                    PROCESS8(0)
                    if (m > 8) PROCESS8(8)
                    base += 16;
                    if (base >= end) break;
                    int mn = end - base; if (mn > 16) mn = 16;
                    int2 p = nt_load_int2(&csr[base + (glane < mn ? glane : mn - 1)]);
                    cp = p;
                    cc = (glane < mn) ? __int_as_float(p.y) : 0.0f;
                }
            }
            float cg = cagg[node];
            #pragma unroll
            for (int t = 0; t < 8; t++) {
                int c = glane * 8 + t;
                o[t] = (_Float16)fmaf(s_bnw[c], acc[t], s_bnu[c] * cg);
            }
        } else {
            #pragma unroll
            for (int t = 0; t < 8; t++) o[t] = (_Float16)0.0f;
        }
        *(half8*)&Alds[grp * 136 + glane * 8] = o;
    }
    #undef PROCESS8
    __syncthreads();

    // ---- MFMA phase: wave w -> 16 rows x col quarter [w*32, w*32+32) ----
    int w = tid >> 6, l64 = tid & 63;
    int quad = l64 >> 4, l16 = l64 & 15;
    const half8* Bh8 = (const half8*)Whi;
    const half8* Bl8 = (const half8*)Wlo;
    f32x4 acc[2];
    #pragma unroll
    for (int j = 0; j < 2; j++) acc[j] = (f32x4){0.f, 0.f, 0.f, 0.f};
    #pragma unroll
    for (int kc = 0; kc < 4; kc++) {
        half8 a = *(const half8*)&Alds[l16 * 136 + kc * 32 + quad * 8];
        #pragma unroll
        for (int j = 0; j < 2; j++) {
            int ntg = w * 2 + j;
            half8 bh = Bh8[(ntg * 4 + kc) * 64 + l64];
            half8 bl = Bl8[(ntg * 4 + kc) * 64 + l64];
            acc[j] = __builtin_amdgcn_mfma_f32_16x16x32_f16(a, bh, acc[j], 0, 0, 0);
            acc[j] = __builtin_amdgcn_mfma_f32_16x16x32_f16(a, bl, acc[j], 0, 0, 0);
        }
    }
    __syncthreads();   // all waves done reading A-tile; Alds reused as output stage

    // ---- epilogue: bias + rational -> LDS stage + stats (C layout: col=l16, row=quad*4+reg) ----
    float ps[2], pq[2];
    #pragma unroll
    for (int j = 0; j < 2; j++) { ps[j] = 0.0f; pq[j] = 0.0f; }
    #pragma unroll
    for (int reg = 0; reg < 4; reg++) {
        int lrow = quad * 4 + reg;
        int row = r0 + lrow;
        bool live = (row < n);
        #pragma unroll
        for (int j = 0; j < 2; j++) {
            int col = (w * 2 + j) * 16 + l16;
            float v = acc[j][reg] + s_bias[col];
            float r = rational_act(v, s_num + s_cl[col] * 6, s_den + s_cl[col] * 4);
            Alds[lrow * 136 + col] = (_Float16)r;
            if (live) { ps[j] += r; pq[j] = fmaf(r, r, pq[j]); }
        }
    }
    // cross-quad reduce first -> 4x fewer LDS atomics, no same-address serialization
    #pragma unroll
    for (int j = 0; j < 2; j++) {
        float a2 = ps[j] + __shfl_xor(ps[j], 16, 64);
        a2 += __shfl_xor(a2, 32, 64);
        float b2 = pq[j] + __shfl_xor(pq[j], 16, 64);
        b2 += __shfl_xor(b2, 32, 64);
        if (quad == 0) {
            int col = (w * 2 + j) * 16 + l16;
            atomicAdd(&s_sum[col], a2);
            atomicAdd(&s_sq[col], b2);
        }
    }
    __syncthreads();
    // per-block stat partials: contention-free 1KB full-line NT store
    {
        float pv = (tid < 128) ? s_sum[tid] : s_sq[tid - 128];
        __builtin_nontemporal_store(pv, &part[(size_t)blockIdx.x * 256 + tid]);
    }
    // ---- full-line NT stores: 1 x half8 per thread, 256B rows, 256B-aligned base ----
    {
        int lrow = tid >> 4, lc = (tid & 15) * 8;
        int row = r0 + lrow;
        if (row < n) {
            half8 v = *(const half8*)&Alds[lrow * 136 + lc];
            __builtin_nontemporal_store(v, (half8*)&actOut[(size_t)row * HID + lc]);
        }
    }
}

// ---------------- fused pool (+final BN affine from stats) + 3-stage MLP ----------------
__global__ __launch_bounds__(256) void poolmlp_kernel(const _Float16* __restrict__ act,
                                                      const int* __restrict__ gstart,
                                                      const int* __restrict__ gend,
                                                      const float* __restrict__ stat,
                                                      const float* __restrict__ g3,
                                                      const float* __restrict__ be3,
                                                      const float* __restrict__ HW1,
                                                      const float* __restrict__ Hb1,
                                                      const float* __restrict__ HW2,
                                                      const float* __restrict__ Hb2,
                                                      const float* __restrict__ HW3,
                                                      const float* __restrict__ Hb3,
                                                      float* __restrict__ out, int n) {
    __shared__ float red[16][HID];
    __shared__ float s_pool[HID];
    __shared__ float s_z[HID];
    int gi = blockIdx.x;
    int tid = threadIdx.x;
    int rg = tid >> 4, lane = tid & 15;
    int s = gstart[gi], e = gend[gi];
    const half8* act8 = (const half8*)act;
    float a[8];
    #pragma unroll
    for (int t = 0; t < 8; t++) a[t] = 0.0f;
    for (int r = s + rg; r < e; r += 16) {
        half8 v = act8[r * 16 + lane];
        #pragma unroll
        for (int t = 0; t < 8; t++) a[t] += (float)v[t];
    }
    #pragma unroll
    for (int t = 0; t < 8; t++) red[rg][lane * 8 + t] = a[t];
    __syncthreads();
    if (tid < HID) {
        float tot = 0.0f;
        #pragma unroll
        for (int i = 0; i < 16; i++) tot += red[i][tid];
        int cnt = e - s;
        float pooled = 0.0f;
        if (cnt > 0) {
            float inv_n = 1.0f / (float)n;
            float mean = stat[tid] * inv_n;
            float var = stat[HID + tid] * inv_n - mean * mean;
            float w = g3[tid] * rsqrtf(var + 1e-5f);
            float u = be3[tid] - mean * w;
            pooled = fmaf(w, tot / (float)cnt, u);
        }
        s_pool[tid] = pooled;
    }
    __syncthreads();
    if (tid < HID) {
        float acc = Hb1[tid];
        #pragma unroll 8
        for (int k = 0; k < HID; k++) acc = fmaf(s_pool[k], HW1[k * HID + tid], acc);
        s_z[tid] = 0.5f * acc * (1.0f + erff(acc * 0.70710678118654752f));
    }
    __syncthreads();
    if (tid < HID) {
        float acc = Hb2[tid];
        #pragma unroll 8
        for (int k = 0; k < HID; k++) acc = fmaf(s_z[k], HW2[k * HID + tid], acc);
        s_pool[tid] = 0.5f * acc * (1.0f + erff(acc * 0.70710678118654752f));
    }
    __syncthreads();
    if (tid < OUTF) {
        float acc = Hb3[tid];
        #pragma unroll 8
        for (int k = 0; k < HID; k++) acc = fmaf(s_pool[k], HW3[k * OUTF + tid], acc);
        out[gi * OUTF + tid] = acc;
    }
}

extern "C" void kernel_launch(void* const* d_in, const int* in_sizes, int n_in,
                              void* d_out, int out_size, void* d_ws, size_t ws_size,
                              hipStream_t stream) {
    const float* x          = (const float*)d_in[0];
    const int*   edge_index = (const int*)d_in[1];
    const int*   batch      = (const int*)d_in[2];
    const float* W[4]  = {(const float*)d_in[3], (const float*)d_in[7], (const float*)d_in[11], (const float*)d_in[15]};
    const float* bL[4] = {(const float*)d_in[4], (const float*)d_in[8], (const float*)d_in[12], (const float*)d_in[16]};
    const float* gL[4] = {(const float*)d_in[5], (const float*)d_in[9], (const float*)d_in[13], (const float*)d_in[17]};
    const float* beL[4]= {(const float*)d_in[6], (const float*)d_in[10], (const float*)d_in[14], (const float*)d_in[18]};
    const float* rat_num = (const float*)d_in[19];
    const float* rat_den = (const float*)d_in[20];
    const int*   cl_assign = (const int*)d_in[21];
    const float* HW1 = (const float*)d_in[22];
    const float* Hb1 = (const float*)d_in[23];
    const float* HW2 = (const float*)d_in[24];
    const float* Hb2 = (const float*)d_in[25];
    const float* HW3 = (const float*)d_in[26];
    const float* Hb3 = (const float*)d_in[27];
    float* out = (float*)d_out;

    const int N = in_sizes[0] / INF;
    const int E = in_sizes[1] / 2;
    const int NB = (N + 1023) / 1024;
    const int layer_grid = (N + 15) / 16;

    // ---- workspace layout (dword offsets, every buffer 256B-aligned) ----
    char* wsb = (char*)d_ws;
    size_t o = 0;
    #define ALIGNB o = (o + 63) & ~(size_t)63;
    int*   cnt_part = (int*)(wsb + o * 4);  o += (size_t)NPART * N; ALIGNB  // zeroed
    int*   gstart  = (int*)(wsb + o * 4);  o += GRP; ALIGNB         // zeroed
    int*   gend    = (int*)(wsb + o * 4);  o += GRP; ALIGNB         // zeroed
    float* bnstat  = (float*)(wsb + o * 4); o += 4 * 256; ALIGNB    // zeroed
    size_t zero_elems = o;
    int*   bsum    = (int*)(wsb + o * 4);  o += ((NB + 63) & ~63); ALIGNB
    int*   cursor_part = (int*)(wsb + o * 4);  o += (size_t)NPART * N; ALIGNB
    int*   row_ptr = (int*)(wsb + o * 4);  o += N + 1; ALIGNB
    float* dinv    = (float*)(wsb + o * 4); o += N; ALIGNB
    float* cagg    = (float*)(wsb + o * 4); o += N; ALIGNB
    int2*  csr     = (int2*)(wsb + o * 4);  o += 2 * (size_t)E; ALIGNB
    _Float16* WhiAll = (_Float16*)(wsb + o * 4); o += 4 * HID * HID / 2; ALIGNB
    _Float16* WloAll = (_Float16*)(wsb + o * 4); o += 4 * HID * HID / 2; ALIGNB
    _Float16* actA  = (_Float16*)(wsb + o * 4); o += (size_t)N * HID / 2; ALIGNB
    _Float16* actB  = (_Float16*)(wsb + o * 4); o += (size_t)N * HID / 2; ALIGNB
    float* part    = (float*)(wsb + o * 4); o += (size_t)layer_grid * 256;

    hipMemsetAsync(d_ws, 0, zero_elems * 4, stream);

    int eb = (E + 255) / 256;
    hist_prepw_kernel<<<eb, 256, 0, stream>>>(edge_index, cnt_part, E, N, W[1], W[2], W[3],
                                              WhiAll, WloAll);
    scanA_kernel<<<NB, 256, 0, stream>>>(cnt_part, bsum, N);
    scanC_kernel<<<NB, 256, 0, stream>>>(cnt_part, bsum, batch, row_ptr, cursor_part, dinv,
                                         gstart, gend, N);
    fill_kernel<<<eb, 256, 0, stream>>>(edge_index, cursor_part, dinv, csr, E, N);

    // layer 0 (gather + matvec fused, 8-deep unrolled)
    gemm0_fused_kernel<<<layer_grid, 256, 0, stream>>>(x, row_ptr, csr, dinv, W[0], bL[0],
                                                       rat_num, rat_den, cl_assign,
                                                       actA, cagg, part, N);
    statreduce_kernel<<<256, 256, 0, stream>>>(part, layer_grid, bnstat);

    _Float16* ain = actA;
    _Float16* aout = actB;
    for (int l = 1; l < 4; l++) {
        layer_fused_kernel<<<layer_grid, 256, 0, stream>>>(ain, csr, row_ptr, dinv, cagg,
                                                           bnstat + (l - 1) * 256,
                                                           gL[l - 1], beL[l - 1],
                                                           WhiAll + (size_t)l * HID * HID,
                                                           WloAll + (size_t)l * HID * HID,
                                                           bL[l], rat_num, rat_den, cl_assign,
                                                           aout, part, N);
        statreduce_kernel<<<256, 256, 0, stream>>>(part, layer_grid, bnstat + l * 256);
        _Float16* t = ain; ain = aout; aout = t;
    }
    poolmlp_kernel<<<GRP, 256, 0, stream>>>(ain, gstart, gend, bnstat + 3 * 256,
                                            gL[3], beL[3], HW1, Hb1, HW2, Hb2, HW3, Hb3,
                                            out, N);
}

// Round 15
// 425.863 us; speedup vs baseline: 1.1409x; 1.0254x over previous
//
#include <hip/hip_runtime.h>
#include <math.h>

#define HID 128
#define GRP 256
#define INF 9
#define OUTF 10
#define NPART 8

typedef _Float16 half8 __attribute__((ext_vector_type(8)));
typedef _Float16 h2 __attribute__((ext_vector_type(2)));
typedef __attribute__((ext_vector_type(4))) float f32x4;

__device__ __forceinline__ int2 nt_load_int2(const int2* p) {
    long long v = __builtin_nontemporal_load((const long long*)p);
    int2 r; r.x = (int)(v & 0xffffffffLL); r.y = (int)(v >> 32);
    return r;
}

// ---------------- histogram over dst (8-way XCD-partitioned) + W-prep ----------------
__global__ void hist_prepw_kernel(const int* __restrict__ ei, int* __restrict__ cnt_part,
                                  int E, int n,
                                  const float* __restrict__ W1, const float* __restrict__ W2,
                                  const float* __restrict__ W3,
                                  _Float16* __restrict__ Whi, _Float16* __restrict__ Wlo) {
    int e = blockIdx.x * 256 + threadIdx.x;
    if (e < E) atomicAdd(&cnt_part[(size_t)(blockIdx.x & 7) * n + ei[E + e]], 1);
    if (blockIdx.x < 192) {
        int l = blockIdx.x >> 6;                       // 0..2 -> layers 1..3
        int idx = (blockIdx.x & 63) * 256 + threadIdx.x;   // 0..16383
        const float* W = (l == 0) ? W1 : (l == 1) ? W2 : W3;
        int nn = idx >> 7, k = idx & 127;
        float w = W[k * HID + nn];
        _Float16 hi = (_Float16)w;
        _Float16 lo = (_Float16)(w - (float)hi);
        int nt = nn >> 4, l16 = nn & 15;
        int kc = k >> 5, quad = (k >> 3) & 3, j = k & 7;
        size_t off = (size_t)(l + 1) * HID * HID +
                     ((((nt * 4 + kc) * 4 + quad) * 16 + l16) * 8 + j);
        Whi[off] = hi;
        Wlo[off] = lo;
    }
}

// ---------------- parallel scan phase A: per-1024-chunk sums (sums 8 partials) --------
__global__ __launch_bounds__(256) void scanA_kernel(const int* __restrict__ cnt_part,
                                                    int* __restrict__ bsum, int n) {
    int tid = threadIdx.x;
    int base = blockIdx.x * 1024 + tid * 4;
    int s = 0;
    #pragma unroll
    for (int i = 0; i < 4; i++) {
        int idx = base + i;
        if (idx < n) {
            #pragma unroll
            for (int x = 0; x < NPART; x++) s += cnt_part[(size_t)x * n + idx];
        }
    }
    #pragma unroll
    for (int off = 32; off > 0; off >>= 1) s += __shfl_down(s, off);
    __shared__ int ws[4];
    if ((tid & 63) == 0) ws[tid >> 6] = s;
    __syncthreads();
    if (tid == 0) bsum[blockIdx.x] = ws[0] + ws[1] + ws[2] + ws[3];
}

// ---------------- phase C: local scan + per-block prefix of RAW bsum (no scanB) -------
__global__ __launch_bounds__(256) void scanC_kernel(const int* __restrict__ cnt_part,
                                                    const int* __restrict__ bsum,
                                                    const int* __restrict__ batch,
                                                    int* __restrict__ row_ptr,
                                                    int* __restrict__ cursor_part,
                                                    float* __restrict__ dinv,
                                                    int* __restrict__ gstart,
                                                    int* __restrict__ gend, int n) {
    int tid = threadIdx.x;
    int lane = tid & 63, wid = tid >> 6;
    int idx0 = blockIdx.x * 1024 + tid * 4;
    int v[4];
    #pragma unroll
    for (int i = 0; i < 4; i++) {
        int idx = idx0 + i;
        int s = 0;
        if (idx < n) {
            #pragma unroll
            for (int x = 0; x < NPART; x++) s += cnt_part[(size_t)x * n + idx];
        }
        v[i] = s;
    }
    int s = v[0] + v[1] + v[2] + v[3];
    int ps = s;
    #pragma unroll
    for (int off = 1; off < 64; off <<= 1) {
        int t = __shfl_up(ps, off);
        if (lane >= off) ps += t;
    }
    // per-block prefix over raw bsum (sum of chunks before this one)
    int pv = (tid < blockIdx.x) ? bsum[tid] : 0;
    #pragma unroll
    for (int off = 32; off > 0; off >>= 1) pv += __shfl_down(pv, off);
    __shared__ int wsum[4];
    __shared__ int wpre[4];
    if (lane == 63) wsum[wid] = ps;
    if (lane == 0) wpre[wid] = pv;
    __syncthreads();
    int pre = wpre[0] + wpre[1] + wpre[2] + wpre[3];
    int woff = 0;
    #pragma unroll
    for (int i = 0; i < 4; i++) if (i < wid) woff += wsum[i];
    int run = pre + woff + (ps - s);
    #pragma unroll
    for (int i = 0; i < 4; i++) {
        int idx = idx0 + i;
        if (idx < n) {
            row_ptr[idx] = run;
            dinv[idx] = rsqrtf((float)(v[i] + 1));
            int b = run;
            #pragma unroll
            for (int x = 0; x < NPART; x++) {
                cursor_part[(size_t)x * n + idx] = b;
                b += cnt_part[(size_t)x * n + idx];
            }
            run += v[i];
            int bt = batch[idx];
            if (idx == 0 || batch[idx - 1] != bt) gstart[bt] = idx;
            if (idx == n - 1 || batch[idx + 1] != bt) {
                gend[bt] = idx + 1;
            }
            if (idx == n - 1) row_ptr[n] = run;   // total = E
        }
    }
}

// ---------------- CSR fill: partitioned cursors; PLAIN cached store ----------------
__global__ void fill_kernel(const int* __restrict__ ei, int* __restrict__ cursor_part,
                            const float* __restrict__ dinv,
                            int2* __restrict__ csr, int E, int n) {
    int e = blockIdx.x * blockDim.x + threadIdx.x;
    if (e >= E) return;
    int s = ei[e], d = ei[E + e];
    int pos = atomicAdd(&cursor_part[(size_t)(blockIdx.x & 7) * n + d], 1);
    long long v = ((long long)__float_as_int(dinv[s] * dinv[d]) << 32) | (unsigned)s;
    *(long long*)&csr[pos] = v;
}

// ---------------- per-column reduce of per-block stat partials ----------------
__global__ __launch_bounds__(256) void statreduce_kernel(const float* __restrict__ part,
                                                         int nb, float* __restrict__ statOut) {
    int j = blockIdx.x;
    int tid = threadIdx.x;
    float s = 0.0f;
    for (int b = tid; b < nb; b += 256) s += part[(size_t)b * 256 + j];
    #pragma unroll
    for (int off = 32; off > 0; off >>= 1) s += __shfl_down(s, off);
    __shared__ float ws[4];
    if ((tid & 63) == 0) ws[tid >> 6] = s;
    __syncthreads();
    if (tid == 0) statOut[j] = ws[0] + ws[1] + ws[2] + ws[3];
}

// ---------------- rational activation ----------------
__device__ __forceinline__ float rational_act(float xv, const float* __restrict__ a,
                                              const float* __restrict__ q) {
    float P = a[5];
    P = fmaf(P, xv, a[4]); P = fmaf(P, xv, a[3]); P = fmaf(P, xv, a[2]);
    P = fmaf(P, xv, a[1]); P = fmaf(P, xv, a[0]);
    float Q = q[3];
    Q = fmaf(Q, xv, q[2]); Q = fmaf(Q, xv, q[1]); Q = fmaf(Q, xv, q[0]);
    Q *= xv;
    return P / (1.0f + fabsf(Q));
}

// ---------------- aggregate x (9 channels) + cagg (v11's proven split kernel) ---------
// v14: restored -- v13's gather+matvec fusion measured SLOWER than this split pair
// (fused ~45us > aggx ~20 + gemm0 ~10 + aggX round-trip): fusion only pays when it
// removes critical-path traffic; the 3.6MB aggX round-trip was cheaper than lost overlap.
__global__ __launch_bounds__(256) void aggx_kernel(const float* __restrict__ x,
                                                   const int* __restrict__ row_ptr,
                                                   const int2* __restrict__ csr,
                                                   const float* __restrict__ dinv,
                                                   float* __restrict__ aggX,
                                                   float* __restrict__ cagg, int n) {
    int tid = threadIdx.x;
    int node = blockIdx.x * 16 + (tid >> 4);
    int lane = tid & 15;
    if (node >= n) return;
    float di = dinv[node];
    float self = di * di;
    float acc = (lane < INF) ? x[node * INF + lane] * self : 0.0f;
    float cfs = self;
    int beg = row_ptr[node], end = row_ptr[node + 1];
    for (int j = beg; j < end; j++) {
        int2 p = nt_load_int2(&csr[j]);
        float cf = __int_as_float(p.y);
        cfs += cf;
        if (lane < INF) acc = fmaf(cf, x[p.x * INF + lane], acc);
    }
    if (lane < INF) aggX[node * INF + lane] = acc;
    if (lane == 0) cagg[node] = cfs;
}

// ---------------- layer-0: aggX(Nx9) @ W0 + b0 -> rational -> act(fp16) + stats -------
__global__ __launch_bounds__(256) void gemm0_kernel(const float* __restrict__ aggX,
                                                    const float* __restrict__ W0,
                                                    const float* __restrict__ b0,
                                                    const float* __restrict__ rat_num,
                                                    const float* __restrict__ rat_den,
                                                    const int* __restrict__ cl_assign,
                                                    _Float16* __restrict__ act,
                                                    float* __restrict__ part, int n) {
    __shared__ float Ws[INF * HID];
    __shared__ float s_num[120], s_den[80];
    __shared__ int s_cl[HID];
    __shared__ float s_b[HID];
    __shared__ float s_sum[HID], s_sq[HID];
    int tid = threadIdx.x;
    for (int i = tid; i < INF * HID; i += 256) Ws[i] = W0[i];
    if (tid < 120) s_num[tid] = rat_num[tid];
    if (tid < 80) s_den[tid] = rat_den[tid];
    if (tid < HID) {
        s_cl[tid] = cl_assign[tid];
        s_b[tid] = b0[tid];
        s_sum[tid] = 0.0f; s_sq[tid] = 0.0f;
    }
    __syncthreads();
    int w = tid >> 6, lane = tid & 63;
    int c0 = lane * 2, c1 = c0 + 1;
    const float* a0 = s_num + s_cl[c0] * 6;
    const float* q0 = s_den + s_cl[c0] * 4;
    const float* a1 = s_num + s_cl[c1] * 6;
    const float* q1 = s_den + s_cl[c1] * 4;
    float psum0 = 0.0f, psq0 = 0.0f, psum1 = 0.0f, psq1 = 0.0f;
    for (int node = blockIdx.x * 4 + w; node < n; node += gridDim.x * 4) {
        float xv[INF];
        #pragma unroll
        for (int k = 0; k < INF; k++) xv[k] = aggX[node * INF + k];
        float acc0 = s_b[c0], acc1 = s_b[c1];
        #pragma unroll
        for (int k = 0; k < INF; k++) {
            acc0 = fmaf(xv[k], Ws[k * HID + c0], acc0);
            acc1 = fmaf(xv[k], Ws[k * HID + c1], acc1);
        }
        float r0 = rational_act(acc0, a0, q0);
        float r1 = rational_act(acc1, a1, q1);
        h2 o; o[0] = (_Float16)r0; o[1] = (_Float16)r1;
        __builtin_nontemporal_store(o, (h2*)&act[(size_t)node * HID + c0]);
        psum0 += r0; psq0 = fmaf(r0, r0, psq0);
        psum1 += r1; psq1 = fmaf(r1, r1, psq1);
    }
    atomicAdd(&s_sum[c0], psum0);
    atomicAdd(&s_sq[c0], psq0);
    atomicAdd(&s_sum[c1], psum1);
    atomicAdd(&s_sq[c1], psq1);
    __syncthreads();
    float pv = (tid < 128) ? s_sum[tid] : s_sq[tid - 128];
    __builtin_nontemporal_store(pv, &part[(size_t)blockIdx.x * 256 + tid]);
}

// ---------------- fused layer (1-3): gather-agg -> LDS A-tile -> fp16 MFMA -> rational ----------------
// 16-row tile + __launch_bounds__(256, 5). Launch-bounds sweep CLOSED:
// (256,5) -> VGPR 48, no spill, ~49us; (256,6) -> mild spill; (256,8) -> heavy spill.
__global__ __launch_bounds__(256, 5) void layer_fused_kernel(const _Float16* __restrict__ act,
                                                          const int2* __restrict__ csr,
                                                          const int* __restrict__ row_ptr,
                                                          const float* __restrict__ dinv,
                                                          const float* __restrict__ cagg,
                                                          const float* __restrict__ statPrev,
                                                          const float* __restrict__ gPrev,
                                                          const float* __restrict__ bePrev,
                                                          const _Float16* __restrict__ Whi,
                                                          const _Float16* __restrict__ Wlo,
                                                          const float* __restrict__ bias,
                                                          const float* __restrict__ rat_num,
                                                          const float* __restrict__ rat_den,
                                                          const int* __restrict__ cl_assign,
                                                          _Float16* __restrict__ actOut,
                                                          float* __restrict__ part, int n) {
    __shared__ _Float16 Alds[16 * 136];
    __shared__ float s_bnw[HID], s_bnu[HID];
    __shared__ float s_num[120], s_den[80];
    __shared__ int s_cl[HID];
    __shared__ float s_bias[HID];
    __shared__ float s_sum[HID], s_sq[HID];
    int tid = threadIdx.x;
    if (tid < 120) s_num[tid] = rat_num[tid];
    if (tid < 80) s_den[tid] = rat_den[tid];
    if (tid < HID) {
        float inv_n = 1.0f / (float)n;
        float mean = statPrev[tid] * inv_n;
        float var = statPrev[HID + tid] * inv_n - mean * mean;
        float w = gPrev[tid] * rsqrtf(var + 1e-5f);
        s_bnw[tid] = w;
        s_bnu[tid] = bePrev[tid] - mean * w;
        s_cl[tid] = cl_assign[tid];
        s_bias[tid] = bias[tid];
        s_sum[tid] = 0.0f; s_sq[tid] = 0.0f;
    }
    __syncthreads();

    int r0 = blockIdx.x * 16;
    int grp = tid >> 4, glane = tid & 15;
    int grpbase = tid & 48;               // group base lane within the wave
    const half8* act8 = (const half8*)act;

    // ---- one node per 16-lane group ----
    int node = r0 + grp;
    int beg = 0, end = 0;
    if (node < n) { beg = row_ptr[node]; end = row_ptr[node + 1]; }
    int2 pfirst = make_int2(0, 0); float cfirst = 0.0f;
    {
        int rem = end - beg;
        if (rem > 0) {
            int m = rem < 16 ? rem : 16;
            int2 p = nt_load_int2(&csr[beg + (glane < m ? glane : m - 1)]);   // clamped
            pfirst = p;
            cfirst = (glane < m) ? __int_as_float(p.y) : 0.0f;  // coef 0 for pad slots
        }
    }

    // process 8 edge-slots [off..off+8) of the current chunk held in (cp, cc)
    #define PROCESS8(off)                                                              \
        {                                                                              \
            int srcs[8]; float cfs[8];                                                 \
            _Pragma("unroll")                                                          \
            for (int u = 0; u < 8; u++) {                                              \
                srcs[u] = __shfl(cp.x, grpbase + (off) + u, 64);                       \
                cfs[u]  = __shfl(cc,   grpbase + (off) + u, 64);                       \
            }                                                                          \
            half8 v[8];                                                                \
            _Pragma("unroll")                                                          \
            for (int u = 0; u < 8; u++) v[u] = act8[srcs[u] * 16 + glane];             \
            _Pragma("unroll")                                                          \
            for (int u = 0; u < 8; u++) {                                              \
                _Pragma("unroll")                                                      \
                for (int t = 0; t < 8; t++)                                            \
                    acc[t] = fmaf(cfs[u], (float)v[u][t], acc[t]);                     \
            }                                                                          \
        }

    {
        half8 o;
        if (node < n) {
            float di = dinv[node];
            float selfc = di * di;
            half8 sv = act8[node * 16 + glane];
            float acc[8];
            #pragma unroll
            for (int t = 0; t < 8; t++) acc[t] = (float)sv[t] * selfc;
            int base = beg;
            if (base < end) {
                int2 cp = pfirst; float cc = cfirst;
                for (;;) {
                    int m = end - base; if (m > 16) m = 16;
                    PROCESS8(0)
                    if (m > 8) PROCESS8(8)
                    base += 16;
                    if (base >= end) break;
                    int mn = end - base; if (mn > 16) mn = 16;
                    int2 p = nt_load_int2(&csr[base + (glane < mn ? glane : mn - 1)]);
                    cp = p;
                    cc = (glane < mn) ? __int_as_float(p.y) : 0.0f;
                }
            }
            float cg = cagg[node];
            #pragma unroll
            for (int t = 0; t < 8; t++) {
                int c = glane * 8 + t;
                o[t] = (_Float16)fmaf(s_bnw[c], acc[t], s_bnu[c] * cg);
            }
        } else {
            #pragma unroll
            for (int t = 0; t < 8; t++) o[t] = (_Float16)0.0f;
        }
        *(half8*)&Alds[grp * 136 + glane * 8] = o;
    }
    #undef PROCESS8
    __syncthreads();

    // ---- MFMA phase: wave w -> 16 rows x col quarter [w*32, w*32+32) ----
    int w = tid >> 6, l64 = tid & 63;
    int quad = l64 >> 4, l16 = l64 & 15;
    const half8* Bh8 = (const half8*)Whi;
    const half8* Bl8 = (const half8*)Wlo;
    f32x4 acc[2];
    #pragma unroll
    for (int j = 0; j < 2; j++) acc[j] = (f32x4){0.f, 0.f, 0.f, 0.f};
    #pragma unroll
    for (int kc = 0; kc < 4; kc++) {
        half8 a = *(const half8*)&Alds[l16 * 136 + kc * 32 + quad * 8];
        #pragma unroll
        for (int j = 0; j < 2; j++) {
            int ntg = w * 2 + j;
            half8 bh = Bh8[(ntg * 4 + kc) * 64 + l64];
            half8 bl = Bl8[(ntg * 4 + kc) * 64 + l64];
            acc[j] = __builtin_amdgcn_mfma_f32_16x16x32_f16(a, bh, acc[j], 0, 0, 0);
            acc[j] = __builtin_amdgcn_mfma_f32_16x16x32_f16(a, bl, acc[j], 0, 0, 0);
        }
    }
    __syncthreads();   // all waves done reading A-tile; Alds reused as output stage

    // ---- epilogue: bias + rational -> LDS stage + stats (C layout: col=l16, row=quad*4+reg) ----
    float ps[2], pq[2];
    #pragma unroll
    for (int j = 0; j < 2; j++) { ps[j] = 0.0f; pq[j] = 0.0f; }
    #pragma unroll
    for (int reg = 0; reg < 4; reg++) {
        int lrow = quad * 4 + reg;
        int row = r0 + lrow;
        bool live = (row < n);
        #pragma unroll
        for (int j = 0; j < 2; j++) {
            int col = (w * 2 + j) * 16 + l16;
            float v = acc[j][reg] + s_bias[col];
            float r = rational_act(v, s_num + s_cl[col] * 6, s_den + s_cl[col] * 4);
            Alds[lrow * 136 + col] = (_Float16)r;
            if (live) { ps[j] += r; pq[j] = fmaf(r, r, pq[j]); }
        }
    }
    // cross-quad reduce first -> 4x fewer LDS atomics, no same-address serialization
    #pragma unroll
    for (int j = 0; j < 2; j++) {
        float a2 = ps[j] + __shfl_xor(ps[j], 16, 64);
        a2 += __shfl_xor(a2, 32, 64);
        float b2 = pq[j] + __shfl_xor(pq[j], 16, 64);
        b2 += __shfl_xor(b2, 32, 64);
        if (quad == 0) {
            int col = (w * 2 + j) * 16 + l16;
            atomicAdd(&s_sum[col], a2);
            atomicAdd(&s_sq[col], b2);
        }
    }
    __syncthreads();
    // per-block stat partials: contention-free 1KB full-line NT store
    {
        float pv = (tid < 128) ? s_sum[tid] : s_sq[tid - 128];
        __builtin_nontemporal_store(pv, &part[(size_t)blockIdx.x * 256 + tid]);
    }
    // ---- full-line NT stores: 1 x half8 per thread, 256B rows, 256B-aligned base ----
    {
        int lrow = tid >> 4, lc = (tid & 15) * 8;
        int row = r0 + lrow;
        if (row < n) {
            half8 v = *(const half8*)&Alds[lrow * 136 + lc];
            __builtin_nontemporal_store(v, (half8*)&actOut[(size_t)row * HID + lc]);
        }
    }
}

// ---------------- fused pool (+final BN affine from stats) + 3-stage MLP ----------------
__global__ __launch_bounds__(256) void poolmlp_kernel(const _Float16* __restrict__ act,
                                                      const int* __restrict__ gstart,
                                                      const int* __restrict__ gend,
                                                      const float* __restrict__ stat,
                                                      const float* __restrict__ g3,
                                                      const float* __restrict__ be3,
                                                      const float* __restrict__ HW1,
                                                      const float* __restrict__ Hb1,
                                                      const float* __restrict__ HW2,
                                                      const float* __restrict__ Hb2,
                                                      const float* __restrict__ HW3,
                                                      const float* __restrict__ Hb3,
                                                      float* __restrict__ out, int n) {
    __shared__ float red[16][HID];
    __shared__ float s_pool[HID];
    __shared__ float s_z[HID];
    int gi = blockIdx.x;
    int tid = threadIdx.x;
    int rg = tid >> 4, lane = tid & 15;
    int s = gstart[gi], e = gend[gi];
    const half8* act8 = (const half8*)act;
    float a[8];
    #pragma unroll
    for (int t = 0; t < 8; t++) a[t] = 0.0f;
    for (int r = s + rg; r < e; r += 16) {
        half8 v = act8[r * 16 + lane];
        #pragma unroll
        for (int t = 0; t < 8; t++) a[t] += (float)v[t];
    }
    #pragma unroll
    for (int t = 0; t < 8; t++) red[rg][lane * 8 + t] = a[t];
    __syncthreads();
    if (tid < HID) {
        float tot = 0.0f;
        #pragma unroll
        for (int i = 0; i < 16; i++) tot += red[i][tid];
        int cnt = e - s;
        float pooled = 0.0f;
        if (cnt > 0) {
            float inv_n = 1.0f / (float)n;
            float mean = stat[tid] * inv_n;
            float var = stat[HID + tid] * inv_n - mean * mean;
            float w = g3[tid] * rsqrtf(var + 1e-5f);
            float u = be3[tid] - mean * w;
            pooled = fmaf(w, tot / (float)cnt, u);
        }
        s_pool[tid] = pooled;
    }
    __syncthreads();
    if (tid < HID) {
        float acc = Hb1[tid];
        #pragma unroll 8
        for (int k = 0; k < HID; k++) acc = fmaf(s_pool[k], HW1[k * HID + tid], acc);
        s_z[tid] = 0.5f * acc * (1.0f + erff(acc * 0.70710678118654752f));
    }
    __syncthreads();
    if (tid < HID) {
        float acc = Hb2[tid];
        #pragma unroll 8
        for (int k = 0; k < HID; k++) acc = fmaf(s_z[k], HW2[k * HID + tid], acc);
        s_pool[tid] = 0.5f * acc * (1.0f + erff(acc * 0.70710678118654752f));
    }
    __syncthreads();
    if (tid < OUTF) {
        float acc = Hb3[tid];
        #pragma unroll 8
        for (int k = 0; k < HID; k++) acc = fmaf(s_pool[k], HW3[k * OUTF + tid], acc);
        out[gi * OUTF + tid] = acc;
    }
}

extern "C" void kernel_launch(void* const* d_in, const int* in_sizes, int n_in,
                              void* d_out, int out_size, void* d_ws, size_t ws_size,
                              hipStream_t stream) {
    const float* x          = (const float*)d_in[0];
    const int*   edge_index = (const int*)d_in[1];
    const int*   batch      = (const int*)d_in[2];
    const float* W[4]  = {(const float*)d_in[3], (const float*)d_in[7], (const float*)d_in[11], (const float*)d_in[15]};
    const float* bL[4] = {(const float*)d_in[4], (const float*)d_in[8], (const float*)d_in[12], (const float*)d_in[16]};
    const float* gL[4] = {(const float*)d_in[5], (const float*)d_in[9], (const float*)d_in[13], (const float*)d_in[17]};
    const float* beL[4]= {(const float*)d_in[6], (const float*)d_in[10], (const float*)d_in[14], (const float*)d_in[18]};
    const float* rat_num = (const float*)d_in[19];
    const float* rat_den = (const float*)d_in[20];
    const int*   cl_assign = (const int*)d_in[21];
    const float* HW1 = (const float*)d_in[22];
    const float* Hb1 = (const float*)d_in[23];
    const float* HW2 = (const float*)d_in[24];
    const float* Hb2 = (const float*)d_in[25];
    const float* HW3 = (const float*)d_in[26];
    const float* Hb3 = (const float*)d_in[27];
    float* out = (float*)d_out;

    const int N = in_sizes[0] / INF;
    const int E = in_sizes[1] / 2;
    const int NB = (N + 1023) / 1024;
    const int layer_grid = (N + 15) / 16;

    // ---- workspace layout (dword offsets, every buffer 256B-aligned) ----
    char* wsb = (char*)d_ws;
    size_t o = 0;
    #define ALIGNB o = (o + 63) & ~(size_t)63;
    int*   cnt_part = (int*)(wsb + o * 4);  o += (size_t)NPART * N; ALIGNB  // zeroed
    int*   gstart  = (int*)(wsb + o * 4);  o += GRP; ALIGNB         // zeroed
    int*   gend    = (int*)(wsb + o * 4);  o += GRP; ALIGNB         // zeroed
    float* bnstat  = (float*)(wsb + o * 4); o += 4 * 256; ALIGNB    // zeroed
    size_t zero_elems = o;
    int*   bsum    = (int*)(wsb + o * 4);  o += ((NB + 63) & ~63); ALIGNB
    int*   cursor_part = (int*)(wsb + o * 4);  o += (size_t)NPART * N; ALIGNB
    int*   row_ptr = (int*)(wsb + o * 4);  o += N + 1; ALIGNB
    float* dinv    = (float*)(wsb + o * 4); o += N; ALIGNB
    float* cagg    = (float*)(wsb + o * 4); o += N; ALIGNB
    int2*  csr     = (int2*)(wsb + o * 4);  o += 2 * (size_t)E; ALIGNB
    float* aggX    = (float*)(wsb + o * 4); o += (size_t)N * INF; ALIGNB
    _Float16* WhiAll = (_Float16*)(wsb + o * 4); o += 4 * HID * HID / 2; ALIGNB
    _Float16* WloAll = (_Float16*)(wsb + o * 4); o += 4 * HID * HID / 2; ALIGNB
    _Float16* actA  = (_Float16*)(wsb + o * 4); o += (size_t)N * HID / 2; ALIGNB
    _Float16* actB  = (_Float16*)(wsb + o * 4); o += (size_t)N * HID / 2; ALIGNB
    float* part    = (float*)(wsb + o * 4); o += (size_t)layer_grid * 256;

    hipMemsetAsync(d_ws, 0, zero_elems * 4, stream);

    int eb = (E + 255) / 256;
    hist_prepw_kernel<<<eb, 256, 0, stream>>>(edge_index, cnt_part, E, N, W[1], W[2], W[3],
                                              WhiAll, WloAll);
    scanA_kernel<<<NB, 256, 0, stream>>>(cnt_part, bsum, N);
    scanC_kernel<<<NB, 256, 0, stream>>>(cnt_part, bsum, batch, row_ptr, cursor_part, dinv,
                                         gstart, gend, N);
    fill_kernel<<<eb, 256, 0, stream>>>(edge_index, cursor_part, dinv, csr, E, N);

    // layer 0 (split aggregate + matvec -- measured faster than the fused variant)
    aggx_kernel<<<(N + 15) / 16, 256, 0, stream>>>(x, row_ptr, csr, dinv, aggX, cagg, N);
    gemm0_kernel<<<1024, 256, 0, stream>>>(aggX, W[0], bL[0], rat_num, rat_den,
                                           cl_assign, actA, part, N);
    statreduce_kernel<<<256, 256, 0, stream>>>(part, 1024, bnstat);

    _Float16* ain = actA;
    _Float16* aout = actB;
    for (int l = 1; l < 4; l++) {
        layer_fused_kernel<<<layer_grid, 256, 0, stream>>>(ain, csr, row_ptr, dinv, cagg,
                                                           bnstat + (l - 1) * 256,
                                                           gL[l - 1], beL[l - 1],
                                                           WhiAll + (size_t)l * HID * HID,
                                                           WloAll + (size_t)l * HID * HID,
                                                           bL[l], rat_num, rat_den, cl_assign,
                                                           aout, part, N);
        statreduce_kernel<<<256, 256, 0, stream>>>(part, layer_grid, bnstat + l * 256);
        _Float16* t = ain; ain = aout; aout = t;
    }
    poolmlp_kernel<<<GRP, 256, 0, stream>>>(ain, gstart, gend, bnstat + 3 * 256,
                                            gL[3], beL[3], HW1, Hb1, HW2, Hb2, HW3, Hb3,
                                            out, N);
}

// Round 16
// 412.317 us; speedup vs baseline: 1.1784x; 1.0329x over previous
//
#include <hip/hip_runtime.h>
#include <math.h>

#define HID 128
#define GRP 256
#define INF 9
#define OUTF 10
#define NPART 8

typedef _Float16 half8 __attribute__((ext_vector_type(8)));
typedef _Float16 h2 __attribute__((ext_vector_type(2)));
typedef __attribute__((ext_vector_type(4))) float f32x4;

__device__ __forceinline__ int2 nt_load_int2(const int2* p) {
    long long v = __builtin_nontemporal_load((const long long*)p);
    int2 r; r.x = (int)(v & 0xffffffffLL); r.y = (int)(v >> 32);
    return r;
}

// ---------------- histogram over dst (8-way XCD-partitioned) + W-prep ----------------
__global__ void hist_prepw_kernel(const int* __restrict__ ei, int* __restrict__ cnt_part,
                                  int E, int n,
                                  const float* __restrict__ W1, const float* __restrict__ W2,
                                  const float* __restrict__ W3,
                                  _Float16* __restrict__ Whi, _Float16* __restrict__ Wlo) {
    int e = blockIdx.x * 256 + threadIdx.x;
    if (e < E) atomicAdd(&cnt_part[(size_t)(blockIdx.x & 7) * n + ei[E + e]], 1);
    if (blockIdx.x < 192) {
        int l = blockIdx.x >> 6;                       // 0..2 -> layers 1..3
        int idx = (blockIdx.x & 63) * 256 + threadIdx.x;   // 0..16383
        const float* W = (l == 0) ? W1 : (l == 1) ? W2 : W3;
        int nn = idx >> 7, k = idx & 127;
        float w = W[k * HID + nn];
        _Float16 hi = (_Float16)w;
        _Float16 lo = (_Float16)(w - (float)hi);
        int nt = nn >> 4, l16 = nn & 15;
        int kc = k >> 5, quad = (k >> 3) & 3, j = k & 7;
        size_t off = (size_t)(l + 1) * HID * HID +
                     ((((nt * 4 + kc) * 4 + quad) * 16 + l16) * 8 + j);
        Whi[off] = hi;
        Wlo[off] = lo;
    }
}

// ---------------- parallel scan phase A: per-1024-chunk sums (sums 8 partials) --------
__global__ __launch_bounds__(256) void scanA_kernel(const int* __restrict__ cnt_part,
                                                    int* __restrict__ bsum, int n) {
    int tid = threadIdx.x;
    int base = blockIdx.x * 1024 + tid * 4;
    int s = 0;
    #pragma unroll
    for (int i = 0; i < 4; i++) {
        int idx = base + i;
        if (idx < n) {
            #pragma unroll
            for (int x = 0; x < NPART; x++) s += cnt_part[(size_t)x * n + idx];
        }
    }
    #pragma unroll
    for (int off = 32; off > 0; off >>= 1) s += __shfl_down(s, off);
    __shared__ int ws[4];
    if ((tid & 63) == 0) ws[tid >> 6] = s;
    __syncthreads();
    if (tid == 0) bsum[blockIdx.x] = ws[0] + ws[1] + ws[2] + ws[3];
}

// ---------------- phase C: local scan + per-block prefix of RAW bsum (no scanB) -------
__global__ __launch_bounds__(256) void scanC_kernel(const int* __restrict__ cnt_part,
                                                    const int* __restrict__ bsum,
                                                    const int* __restrict__ batch,
                                                    int* __restrict__ row_ptr,
                                                    int* __restrict__ cursor_part,
                                                    float* __restrict__ dinv,
                                                    int* __restrict__ gstart,
                                                    int* __restrict__ gend, int n) {
    int tid = threadIdx.x;
    int lane = tid & 63, wid = tid >> 6;
    int idx0 = blockIdx.x * 1024 + tid * 4;
    int v[4];
    #pragma unroll
    for (int i = 0; i < 4; i++) {
        int idx = idx0 + i;
        int s = 0;
        if (idx < n) {
            #pragma unroll
            for (int x = 0; x < NPART; x++) s += cnt_part[(size_t)x * n + idx];
        }
        v[i] = s;
    }
    int s = v[0] + v[1] + v[2] + v[3];
    int ps = s;
    #pragma unroll
    for (int off = 1; off < 64; off <<= 1) {
        int t = __shfl_up(ps, off);
        if (lane >= off) ps += t;
    }
    // per-block prefix over raw bsum (sum of chunks before this one)
    int pv = (tid < blockIdx.x) ? bsum[tid] : 0;
    #pragma unroll
    for (int off = 32; off > 0; off >>= 1) pv += __shfl_down(pv, off);
    __shared__ int wsum[4];
    __shared__ int wpre[4];
    if (lane == 63) wsum[wid] = ps;
    if (lane == 0) wpre[wid] = pv;
    __syncthreads();
    int pre = wpre[0] + wpre[1] + wpre[2] + wpre[3];
    int woff = 0;
    #pragma unroll
    for (int i = 0; i < 4; i++) if (i < wid) woff += wsum[i];
    int run = pre + woff + (ps - s);
    #pragma unroll
    for (int i = 0; i < 4; i++) {
        int idx = idx0 + i;
        if (idx < n) {
            row_ptr[idx] = run;
            dinv[idx] = rsqrtf((float)(v[i] + 1));
            int b = run;
            #pragma unroll
            for (int x = 0; x < NPART; x++) {
                cursor_part[(size_t)x * n + idx] = b;
                b += cnt_part[(size_t)x * n + idx];
            }
            run += v[i];
            int bt = batch[idx];
            if (idx == 0 || batch[idx - 1] != bt) gstart[bt] = idx;
            if (idx == n - 1 || batch[idx + 1] != bt) {
                gend[bt] = idx + 1;
            }
            if (idx == n - 1) row_ptr[n] = run;   // total = E
        }
    }
}

// ---------------- CSR fill: partitioned cursors; PLAIN cached store ----------------
__global__ void fill_kernel(const int* __restrict__ ei, int* __restrict__ cursor_part,
                            const float* __restrict__ dinv,
                            int2* __restrict__ csr, int E, int n) {
    int e = blockIdx.x * blockDim.x + threadIdx.x;
    if (e >= E) return;
    int s = ei[e], d = ei[E + e];
    int pos = atomicAdd(&cursor_part[(size_t)(blockIdx.x & 7) * n + d], 1);
    long long v = ((long long)__float_as_int(dinv[s] * dinv[d]) << 32) | (unsigned)s;
    *(long long*)&csr[pos] = v;
}

// ---------------- per-column reduce of per-block stat partials ----------------
__global__ __launch_bounds__(256) void statreduce_kernel(const float* __restrict__ part,
                                                         int nb, float* __restrict__ statOut) {
    int j = blockIdx.x;
    int tid = threadIdx.x;
    float s = 0.0f;
    for (int b = tid; b < nb; b += 256) s += part[(size_t)b * 256 + j];
    #pragma unroll
    for (int off = 32; off > 0; off >>= 1) s += __shfl_down(s, off);
    __shared__ float ws[4];
    if ((tid & 63) == 0) ws[tid >> 6] = s;
    __syncthreads();
    if (tid == 0) statOut[j] = ws[0] + ws[1] + ws[2] + ws[3];
}

// ---------------- rational activation ----------------
__device__ __forceinline__ float rational_act(float xv, const float* __restrict__ a,
                                              const float* __restrict__ q) {
    float P = a[5];
    P = fmaf(P, xv, a[4]); P = fmaf(P, xv, a[3]); P = fmaf(P, xv, a[2]);
    P = fmaf(P, xv, a[1]); P = fmaf(P, xv, a[0]);
    float Q = q[3];
    Q = fmaf(Q, xv, q[2]); Q = fmaf(Q, xv, q[1]); Q = fmaf(Q, xv, q[0]);
    Q *= xv;
    return P / (1.0f + fabsf(Q));
}

// ---------------- aggregate x (9 channels) + cagg -- v15: 8-deep unrolled gather ------
// Applies the layer kernel's proven PROCESS8 pattern (v1->v2 lesson: serial csr->x chain
// is the latency killer): clamped 16-edge register chunk, shfl broadcast, 8 independent
// x-row loads in flight per 16-lane group.
__global__ __launch_bounds__(256) void aggx_kernel(const float* __restrict__ x,
                                                   const int* __restrict__ row_ptr,
                                                   const int2* __restrict__ csr,
                                                   const float* __restrict__ dinv,
                                                   float* __restrict__ aggX,
                                                   float* __restrict__ cagg, int n) {
    int tid = threadIdx.x;
    int grp = tid >> 4, glane = tid & 15;
    int grpbase = tid & 48;               // group base lane within the wave
    int node = blockIdx.x * 16 + grp;
    int beg = 0, end = 0;
    if (node < n) { beg = row_ptr[node]; end = row_ptr[node + 1]; }
    int2 pfirst = make_int2(0, 0); float cfirst = 0.0f;
    {
        int rem = end - beg;
        if (rem > 0) {
            int m = rem < 16 ? rem : 16;
            int2 p = nt_load_int2(&csr[beg + (glane < m ? glane : m - 1)]);   // clamped
            pfirst = p;
            cfirst = (glane < m) ? __int_as_float(p.y) : 0.0f;  // coef 0 for pad slots
        }
    }

    #define GPROC8(off)                                                                \
        {                                                                              \
            int srcs[8]; float cfv[8];                                                 \
            _Pragma("unroll")                                                          \
            for (int u = 0; u < 8; u++) {                                              \
                srcs[u] = __shfl(cp.x, grpbase + (off) + u, 64);                       \
                cfv[u]  = __shfl(cc,   grpbase + (off) + u, 64);                       \
            }                                                                          \
            float xv[8];                                                               \
            _Pragma("unroll")                                                          \
            for (int u = 0; u < 8; u++)                                                \
                xv[u] = (glane < INF) ? x[(size_t)srcs[u] * INF + glane] : 0.0f;       \
            _Pragma("unroll")                                                          \
            for (int u = 0; u < 8; u++) {                                              \
                cfs += cfv[u];                                                         \
                acc = fmaf(cfv[u], xv[u], acc);                                        \
            }                                                                          \
        }

    if (node < n) {
        float di = dinv[node];
        float self = di * di;
        float acc = (glane < INF) ? x[(size_t)node * INF + glane] * self : 0.0f;
        float cfs = self;
        int base = beg;
        if (base < end) {
            int2 cp = pfirst; float cc = cfirst;
            for (;;) {
                int m = end - base; if (m > 16) m = 16;
                GPROC8(0)
                if (m > 8) GPROC8(8)
                base += 16;
                if (base >= end) break;
                int mn = end - base; if (mn > 16) mn = 16;
                int2 p = nt_load_int2(&csr[base + (glane < mn ? glane : mn - 1)]);
                cp = p;
                cc = (glane < mn) ? __int_as_float(p.y) : 0.0f;
            }
        }
        if (glane < INF) aggX[(size_t)node * INF + glane] = acc;
        if (glane == 0) cagg[node] = cfs;
    }
    #undef GPROC8
}

// ---------------- layer-0: aggX(Nx9) @ W0 + b0 -> rational -> act(fp16) + stats -------
__global__ __launch_bounds__(256) void gemm0_kernel(const float* __restrict__ aggX,
                                                    const float* __restrict__ W0,
                                                    const float* __restrict__ b0,
                                                    const float* __restrict__ rat_num,
                                                    const float* __restrict__ rat_den,
                                                    const int* __restrict__ cl_assign,
                                                    _Float16* __restrict__ act,
                                                    float* __restrict__ part, int n) {
    __shared__ float Ws[INF * HID];
    __shared__ float s_num[120], s_den[80];
    __shared__ int s_cl[HID];
    __shared__ float s_b[HID];
    __shared__ float s_sum[HID], s_sq[HID];
    int tid = threadIdx.x;
    for (int i = tid; i < INF * HID; i += 256) Ws[i] = W0[i];
    if (tid < 120) s_num[tid] = rat_num[tid];
    if (tid < 80) s_den[tid] = rat_den[tid];
    if (tid < HID) {
        s_cl[tid] = cl_assign[tid];
        s_b[tid] = b0[tid];
        s_sum[tid] = 0.0f; s_sq[tid] = 0.0f;
    }
    __syncthreads();
    int w = tid >> 6, lane = tid & 63;
    int c0 = lane * 2, c1 = c0 + 1;
    const float* a0 = s_num + s_cl[c0] * 6;
    const float* q0 = s_den + s_cl[c0] * 4;
    const float* a1 = s_num + s_cl[c1] * 6;
    const float* q1 = s_den + s_cl[c1] * 4;
    float psum0 = 0.0f, psq0 = 0.0f, psum1 = 0.0f, psq1 = 0.0f;
    for (int node = blockIdx.x * 4 + w; node < n; node += gridDim.x * 4) {
        float xv[INF];
        #pragma unroll
        for (int k = 0; k < INF; k++) xv[k] = aggX[node * INF + k];
        float acc0 = s_b[c0], acc1 = s_b[c1];
        #pragma unroll
        for (int k = 0; k < INF; k++) {
            acc0 = fmaf(xv[k], Ws[k * HID + c0], acc0);
            acc1 = fmaf(xv[k], Ws[k * HID + c1], acc1);
        }
        float r0 = rational_act(acc0, a0, q0);
        float r1 = rational_act(acc1, a1, q1);
        h2 o; o[0] = (_Float16)r0; o[1] = (_Float16)r1;
        __builtin_nontemporal_store(o, (h2*)&act[(size_t)node * HID + c0]);
        psum0 += r0; psq0 = fmaf(r0, r0, psq0);
        psum1 += r1; psq1 = fmaf(r1, r1, psq1);
    }
    atomicAdd(&s_sum[c0], psum0);
    atomicAdd(&s_sq[c0], psq0);
    atomicAdd(&s_sum[c1], psum1);
    atomicAdd(&s_sq[c1], psq1);
    __syncthreads();
    float pv = (tid < 128) ? s_sum[tid] : s_sq[tid - 128];
    __builtin_nontemporal_store(pv, &part[(size_t)blockIdx.x * 256 + tid]);
}

// ---------------- fused layer (1-3): gather-agg -> LDS A-tile -> fp16 MFMA -> rational ----------------
// 16-row tile + __launch_bounds__(256, 5). Launch-bounds sweep CLOSED:
// (256,5) -> VGPR 48, no spill, ~48us; (256,6) -> mild spill; (256,8) -> heavy spill.
__global__ __launch_bounds__(256, 5) void layer_fused_kernel(const _Float16* __restrict__ act,
                                                          const int2* __restrict__ csr,
                                                          const int* __restrict__ row_ptr,
                                                          const float* __restrict__ dinv,
                                                          const float* __restrict__ cagg,
                                                          const float* __restrict__ statPrev,
                                                          const float* __restrict__ gPrev,
                                                          const float* __restrict__ bePrev,
                                                          const _Float16* __restrict__ Whi,
                                                          const _Float16* __restrict__ Wlo,
                                                          const float* __restrict__ bias,
                                                          const float* __restrict__ rat_num,
                                                          const float* __restrict__ rat_den,
                                                          const int* __restrict__ cl_assign,
                                                          _Float16* __restrict__ actOut,
                                                          float* __restrict__ part, int n) {
    __shared__ _Float16 Alds[16 * 136];
    __shared__ float s_bnw[HID], s_bnu[HID];
    __shared__ float s_num[120], s_den[80];
    __shared__ int s_cl[HID];
    __shared__ float s_bias[HID];
    __shared__ float s_sum[HID], s_sq[HID];
    int tid = threadIdx.x;
    if (tid < 120) s_num[tid] = rat_num[tid];
    if (tid < 80) s_den[tid] = rat_den[tid];
    if (tid < HID) {
        float inv_n = 1.0f / (float)n;
        float mean = statPrev[tid] * inv_n;
        float var = statPrev[HID + tid] * inv_n - mean * mean;
        float w = gPrev[tid] * rsqrtf(var + 1e-5f);
        s_bnw[tid] = w;
        s_bnu[tid] = bePrev[tid] - mean * w;
        s_cl[tid] = cl_assign[tid];
        s_bias[tid] = bias[tid];
        s_sum[tid] = 0.0f; s_sq[tid] = 0.0f;
    }
    __syncthreads();

    int r0 = blockIdx.x * 16;
    int grp = tid >> 4, glane = tid & 15;
    int grpbase = tid & 48;               // group base lane within the wave
    const half8* act8 = (const half8*)act;

    // ---- one node per 16-lane group ----
    int node = r0 + grp;
    int beg = 0, end = 0;
    if (node < n) { beg = row_ptr[node]; end = row_ptr[node + 1]; }
    int2 pfirst = make_int2(0, 0); float cfirst = 0.0f;
    {
        int rem = end - beg;
        if (rem > 0) {
            int m = rem < 16 ? rem : 16;
            int2 p = nt_load_int2(&csr[beg + (glane < m ? glane : m - 1)]);   // clamped
            pfirst = p;
            cfirst = (glane < m) ? __int_as_float(p.y) : 0.0f;  // coef 0 for pad slots
        }
    }

    // process 8 edge-slots [off..off+8) of the current chunk held in (cp, cc)
    #define PROCESS8(off)                                                              \
        {                                                                              \
            int srcs[8]; float cfs[8];                                                 \
            _Pragma("unroll")                                                          \
            for (int u = 0; u < 8; u++) {                                              \
                srcs[u] = __shfl(cp.x, grpbase + (off) + u, 64);                       \
                cfs[u]  = __shfl(cc,   grpbase + (off) + u, 64);                       \
            }                                                                          \
            half8 v[8];                                                                \
            _Pragma("unroll")                                                          \
            for (int u = 0; u < 8; u++) v[u] = act8[srcs[u] * 16 + glane];             \
            _Pragma("unroll")                                                          \
            for (int u = 0; u < 8; u++) {                                              \
                _Pragma("unroll")                                                      \
                for (int t = 0; t < 8; t++)                                            \
                    acc[t] = fmaf(cfs[u], (float)v[u][t], acc[t]);                     \
            }                                                                          \
        }

    {
        half8 o;
        if (node < n) {
            float di = dinv[node];
            float selfc = di * di;
            half8 sv = act8[node * 16 + glane];
            float acc[8];
            #pragma unroll
            for (int t = 0; t < 8; t++) acc[t] = (float)sv[t] * selfc;
            int base = beg;
            if (base < end) {
                int2 cp = pfirst; float cc = cfirst;
                for (;;) {
                    int m = end - base; if (m > 16) m = 16;
                    PROCESS8(0)
                    if (m > 8) PROCESS8(8)
                    base += 16;
                    if (base >= end) break;
                    int mn = end - base; if (mn > 16) mn = 16;
                    int2 p = nt_load_int2(&csr[base + (glane < mn ? glane : mn - 1)]);
                    cp = p;
                    cc = (glane < mn) ? __int_as_float(p.y) : 0.0f;
                }
            }
            float cg = cagg[node];
            #pragma unroll
            for (int t = 0; t < 8; t++) {
                int c = glane * 8 + t;
                o[t] = (_Float16)fmaf(s_bnw[c], acc[t], s_bnu[c] * cg);
            }
        } else {
            #pragma unroll
            for (int t = 0; t < 8; t++) o[t] = (_Float16)0.0f;
        }
        *(half8*)&Alds[grp * 136 + glane * 8] = o;
    }
    #undef PROCESS8
    __syncthreads();

    // ---- MFMA phase: wave w -> 16 rows x col quarter [w*32, w*32+32) ----
    int w = tid >> 6, l64 = tid & 63;
    int quad = l64 >> 4, l16 = l64 & 15;
    const half8* Bh8 = (const half8*)Whi;
    const half8* Bl8 = (const half8*)Wlo;
    f32x4 acc[2];
    #pragma unroll
    for (int j = 0; j < 2; j++) acc[j] = (f32x4){0.f, 0.f, 0.f, 0.f};
    #pragma unroll
    for (int kc = 0; kc < 4; kc++) {
        half8 a = *(const half8*)&Alds[l16 * 136 + kc * 32 + quad * 8];
        #pragma unroll
        for (int j = 0; j < 2; j++) {
            int ntg = w * 2 + j;
            half8 bh = Bh8[(ntg * 4 + kc) * 64 + l64];
            half8 bl = Bl8[(ntg * 4 + kc) * 64 + l64];
            acc[j] = __builtin_amdgcn_mfma_f32_16x16x32_f16(a, bh, acc[j], 0, 0, 0);
            acc[j] = __builtin_amdgcn_mfma_f32_16x16x32_f16(a, bl, acc[j], 0, 0, 0);
        }
    }
    __syncthreads();   // all waves done reading A-tile; Alds reused as output stage

    // ---- epilogue: bias + rational -> LDS stage + stats (C layout: col=l16, row=quad*4+reg) ----
    float ps[2], pq[2];
    #pragma unroll
    for (int j = 0; j < 2; j++) { ps[j] = 0.0f; pq[j] = 0.0f; }
    #pragma unroll
    for (int reg = 0; reg < 4; reg++) {
        int lrow = quad * 4 + reg;
        int row = r0 + lrow;
        bool live = (row < n);
        #pragma unroll
        for (int j = 0; j < 2; j++) {
            int col = (w * 2 + j) * 16 + l16;
            float v = acc[j][reg] + s_bias[col];
            float r = rational_act(v, s_num + s_cl[col] * 6, s_den + s_cl[col] * 4);
            Alds[lrow * 136 + col] = (_Float16)r;
            if (live) { ps[j] += r; pq[j] = fmaf(r, r, pq[j]); }
        }
    }
    // cross-quad reduce first -> 4x fewer LDS atomics, no same-address serialization
    #pragma unroll
    for (int j = 0; j < 2; j++) {
        float a2 = ps[j] + __shfl_xor(ps[j], 16, 64);
        a2 += __shfl_xor(a2, 32, 64);
        float b2 = pq[j] + __shfl_xor(pq[j], 16, 64);
        b2 += __shfl_xor(b2, 32, 64);
        if (quad == 0) {
            int col = (w * 2 + j) * 16 + l16;
            atomicAdd(&s_sum[col], a2);
            atomicAdd(&s_sq[col], b2);
        }
    }
    __syncthreads();
    // per-block stat partials: contention-free 1KB full-line NT store
    {
        float pv = (tid < 128) ? s_sum[tid] : s_sq[tid - 128];
        __builtin_nontemporal_store(pv, &part[(size_t)blockIdx.x * 256 + tid]);
    }
    // ---- full-line NT stores: 1 x half8 per thread, 256B rows, 256B-aligned base ----
    {
        int lrow = tid >> 4, lc = (tid & 15) * 8;
        int row = r0 + lrow;
        if (row < n) {
            half8 v = *(const half8*)&Alds[lrow * 136 + lc];
            __builtin_nontemporal_store(v, (half8*)&actOut[(size_t)row * HID + lc]);
        }
    }
}

// ---------------- fused pool (+final BN affine from stats) + 3-stage MLP ----------------
__global__ __launch_bounds__(256) void poolmlp_kernel(const _Float16* __restrict__ act,
                                                      const int* __restrict__ gstart,
                                                      const int* __restrict__ gend,
                                                      const float* __restrict__ stat,
                                                      const float* __restrict__ g3,
                                                      const float* __restrict__ be3,
                                                      const float* __restrict__ HW1,
                                                      const float* __restrict__ Hb1,
                                                      const float* __restrict__ HW2,
                                                      const float* __restrict__ Hb2,
                                                      const float* __restrict__ HW3,
                                                      const float* __restrict__ Hb3,
                                                      float* __restrict__ out, int n) {
    __shared__ float red[16][HID];
    __shared__ float s_pool[HID];
    __shared__ float s_z[HID];
    int gi = blockIdx.x;
    int tid = threadIdx.x;
    int rg = tid >> 4, lane = tid & 15;
    int s = gstart[gi], e = gend[gi];
    const half8* act8 = (const half8*)act;
    float a[8];
    #pragma unroll
    for (int t = 0; t < 8; t++) a[t] = 0.0f;
    for (int r = s + rg; r < e; r += 16) {
        half8 v = act8[r * 16 + lane];
        #pragma unroll
        for (int t = 0; t < 8; t++) a[t] += (float)v[t];
    }
    #pragma unroll
    for (int t = 0; t < 8; t++) red[rg][lane * 8 + t] = a[t];
    __syncthreads();
    if (tid < HID) {
        float tot = 0.0f;
        #pragma unroll
        for (int i = 0; i < 16; i++) tot += red[i][tid];
        int cnt = e - s;
        float pooled = 0.0f;
        if (cnt > 0) {
            float inv_n = 1.0f / (float)n;
            float mean = stat[tid] * inv_n;
            float var = stat[HID + tid] * inv_n - mean * mean;
            float w = g3[tid] * rsqrtf(var + 1e-5f);
            float u = be3[tid] - mean * w;
            pooled = fmaf(w, tot / (float)cnt, u);
        }
        s_pool[tid] = pooled;
    }
    __syncthreads();
    if (tid < HID) {
        float acc = Hb1[tid];
        #pragma unroll 8
        for (int k = 0; k < HID; k++) acc = fmaf(s_pool[k], HW1[k * HID + tid], acc);
        s_z[tid] = 0.5f * acc * (1.0f + erff(acc * 0.70710678118654752f));
    }
    __syncthreads();
    if (tid < HID) {
        float acc = Hb2[tid];
        #pragma unroll 8
        for (int k = 0; k < HID; k++) acc = fmaf(s_z[k], HW2[k * HID + tid], acc);
        s_pool[tid] = 0.5f * acc * (1.0f + erff(acc * 0.70710678118654752f));
    }
    __syncthreads();
    if (tid < OUTF) {
        float acc = Hb3[tid];
        #pragma unroll 8
        for (int k = 0; k < HID; k++) acc = fmaf(s_pool[k], HW3[k * OUTF + tid], acc);
        out[gi * OUTF + tid] = acc;
    }
}

extern "C" void kernel_launch(void* const* d_in, const int* in_sizes, int n_in,
                              void* d_out, int out_size, void* d_ws, size_t ws_size,
                              hipStream_t stream) {
    const float* x          = (const float*)d_in[0];
    const int*   edge_index = (const int*)d_in[1];
    const int*   batch      = (const int*)d_in[2];
    const float* W[4]  = {(const float*)d_in[3], (const float*)d_in[7], (const float*)d_in[11], (const float*)d_in[15]};
    const float* bL[4] = {(const float*)d_in[4], (const float*)d_in[8], (const float*)d_in[12], (const float*)d_in[16]};
    const float* gL[4] = {(const float*)d_in[5], (const float*)d_in[9], (const float*)d_in[13], (const float*)d_in[17]};
    const float* beL[4]= {(const float*)d_in[6], (const float*)d_in[10], (const float*)d_in[14], (const float*)d_in[18]};
    const float* rat_num = (const float*)d_in[19];
    const float* rat_den = (const float*)d_in[20];
    const int*   cl_assign = (const int*)d_in[21];
    const float* HW1 = (const float*)d_in[22];
    const float* Hb1 = (const float*)d_in[23];
    const float* HW2 = (const float*)d_in[24];
    const float* Hb2 = (const float*)d_in[25];
    const float* HW3 = (const float*)d_in[26];
    const float* Hb3 = (const float*)d_in[27];
    float* out = (float*)d_out;

    const int N = in_sizes[0] / INF;
    const int E = in_sizes[1] / 2;
    const int NB = (N + 1023) / 1024;
    const int layer_grid = (N + 15) / 16;

    // ---- workspace layout (dword offsets, every buffer 256B-aligned) ----
    char* wsb = (char*)d_ws;
    size_t o = 0;
    #define ALIGNB o = (o + 63) & ~(size_t)63;
    int*   cnt_part = (int*)(wsb + o * 4);  o += (size_t)NPART * N; ALIGNB  // zeroed
    int*   gstart  = (int*)(wsb + o * 4);  o += GRP; ALIGNB         // zeroed
    int*   gend    = (int*)(wsb + o * 4);  o += GRP; ALIGNB         // zeroed
    float* bnstat  = (float*)(wsb + o * 4); o += 4 * 256; ALIGNB    // zeroed
    size_t zero_elems = o;
    int*   bsum    = (int*)(wsb + o * 4);  o += ((NB + 63) & ~63); ALIGNB
    int*   cursor_part = (int*)(wsb + o * 4);  o += (size_t)NPART * N; ALIGNB
    int*   row_ptr = (int*)(wsb + o * 4);  o += N + 1; ALIGNB
    float* dinv    = (float*)(wsb + o * 4); o += N; ALIGNB
    float* cagg    = (float*)(wsb + o * 4); o += N; ALIGNB
    int2*  csr     = (int2*)(wsb + o * 4);  o += 2 * (size_t)E; ALIGNB
    float* aggX    = (float*)(wsb + o * 4); o += (size_t)N * INF; ALIGNB
    _Float16* WhiAll = (_Float16*)(wsb + o * 4); o += 4 * HID * HID / 2; ALIGNB
    _Float16* WloAll = (_Float16*)(wsb + o * 4); o += 4 * HID * HID / 2; ALIGNB
    _Float16* actA  = (_Float16*)(wsb + o * 4); o += (size_t)N * HID / 2; ALIGNB
    _Float16* actB  = (_Float16*)(wsb + o * 4); o += (size_t)N * HID / 2; ALIGNB
    float* part    = (float*)(wsb + o * 4); o += (size_t)layer_grid * 256;

    hipMemsetAsync(d_ws, 0, zero_elems * 4, stream);

    int eb = (E + 255) / 256;
    hist_prepw_kernel<<<eb, 256, 0, stream>>>(edge_index, cnt_part, E, N, W[1], W[2], W[3],
                                              WhiAll, WloAll);
    scanA_kernel<<<NB, 256, 0, stream>>>(cnt_part, bsum, N);
    scanC_kernel<<<NB, 256, 0, stream>>>(cnt_part, bsum, batch, row_ptr, cursor_part, dinv,
                                         gstart, gend, N);
    fill_kernel<<<eb, 256, 0, stream>>>(edge_index, cursor_part, dinv, csr, E, N);

    // layer 0 (split aggregate + matvec -- measured faster than the fused variant)
    aggx_kernel<<<(N + 15) / 16, 256, 0, stream>>>(x, row_ptr, csr, dinv, aggX, cagg, N);
    gemm0_kernel<<<1024, 256, 0, stream>>>(aggX, W[0], bL[0], rat_num, rat_den,
                                           cl_assign, actA, part, N);
    statreduce_kernel<<<256, 256, 0, stream>>>(part, 1024, bnstat);

    _Float16* ain = actA;
    _Float16* aout = actB;
    for (int l = 1; l < 4; l++) {
        layer_fused_kernel<<<layer_grid, 256, 0, stream>>>(ain, csr, row_ptr, dinv, cagg,
                                                           bnstat + (l - 1) * 256,
                                                           gL[l - 1], beL[l - 1],
                                                           WhiAll + (size_t)l * HID * HID,
                                                           WloAll + (size_t)l * HID * HID,
                                                           bL[l], rat_num, rat_den, cl_assign,
                                                           aout, part, N);
        statreduce_kernel<<<256, 256, 0, stream>>>(part, layer_grid, bnstat + l * 256);
        _Float16* t = ain; ain = aout; aout = t;
    }
    poolmlp_kernel<<<GRP, 256, 0, stream>>>(ain, gstart, gend, bnstat + 3 * 256,
                                            gL[3], beL[3], HW1, Hb1, HW2, Hb2, HW3, Hb3,
                                            out, N);
}